// Round 4
// baseline (621.322 us; speedup 1.0000x reference)
//
#include <hip/hip_runtime.h>

// MHR_76965813945133: x->QKV proj -> 3x causal MHA (Q<-ctx, K/V fixed) -> out proj.
// B=2, S=2048, D=1024, NH=16, HD=64. bf16 MFMA compute, fp32 accum.
// R4: (1) attn3: 4 waves/block, kt split even/odd across wave pairs (additive
//     partial-O combine, valid because no-max softmax), V-transpose write rotation
//     (bank-conflict-free), 16 waves/CU. (2) GEMMs: bf16 pre-convert kernel +
//     m97-style global_load_lds(16B) staging; out_gemm 128x64 tiles.

#define D_MODEL 1024
#define NHEADS  16
#define HD      64
#define SEQ     2048
#define BATCH   2
#define NROWS   (BATCH*SEQ)   // 4096
#define NQKV    (3*D_MODEL)   // 3072
#define SCL2F   0.1803368801111601f      // 0.125 * log2(e)
#define MASK2   (-14426.950408889634f)   // -10000 * log2(e)

typedef __bf16 bf16x8 __attribute__((ext_vector_type(8)));
typedef float  f32x4  __attribute__((ext_vector_type(4)));
typedef unsigned short us8 __attribute__((ext_vector_type(8)));
typedef short  s16x4  __attribute__((ext_vector_type(4)));

__device__ __forceinline__ unsigned short f2bf(float f) {
  unsigned int u = __float_as_uint(f);
  u = (u + 0x7fffu + ((u >> 16) & 1u)) >> 16;   // RNE
  return (unsigned short)u;
}

union Pack8 { us8 v; unsigned short e[8]; };

__device__ __forceinline__ us8 cvt8(const float4 &a, const float4 &b) {
  Pack8 p;
  p.e[0]=f2bf(a.x); p.e[1]=f2bf(a.y); p.e[2]=f2bf(a.z); p.e[3]=f2bf(a.w);
  p.e[4]=f2bf(b.x); p.e[5]=f2bf(b.y); p.e[6]=f2bf(b.z); p.e[7]=f2bf(b.w);
  return p.v;
}

__device__ __forceinline__ void gl_lds16(const unsigned short* g, unsigned short* l) {
  __builtin_amdgcn_global_load_lds(
      (const __attribute__((address_space(1))) unsigned int*)g,
      (__attribute__((address_space(3))) unsigned int*)l, 16, 0, 0);
}

// ---------------- fp32 -> bf16 pre-convert (x, Wqkv_w, out_w) --------------------
#define CVT_N1 (NROWS*D_MODEL)    // 4194304
#define CVT_N2 (NQKV*D_MODEL)     // 3145728
#define CVT_N3 (D_MODEL*D_MODEL)  // 1048576

__global__ __launch_bounds__(256) void cvt_all(
    const float* __restrict__ x, const float* __restrict__ wq,
    const float* __restrict__ ow,
    unsigned short* __restrict__ xb, unsigned short* __restrict__ wqb,
    unsigned short* __restrict__ owb)
{
  size_t i = ((size_t)blockIdx.x * 256 + threadIdx.x) * 8;
  const float* src; unsigned short* dst; size_t off;
  if (i < CVT_N1)                { src = x;  dst = xb;  off = i; }
  else if (i < CVT_N1 + CVT_N2)  { src = wq; dst = wqb; off = i - CVT_N1; }
  else                           { src = ow; dst = owb; off = i - CVT_N1 - CVT_N2; }
  float4 a = *(const float4*)(src + off);
  float4 b = *(const float4*)(src + off + 4);
  *(us8*)(dst + off) = cvt8(a, b);
}

// ---------------- QKV GEMM: bf16, m97-style async staging ------------------------
// 128x128x32 tiles, 4 waves (2x2), 4x4 frags. As/Bs unpadded (DMA layout).
__global__ __launch_bounds__(256) void qkv_gemm(
    const unsigned short* __restrict__ xb, const unsigned short* __restrict__ wqb,
    const float* __restrict__ bias,
    unsigned short* __restrict__ q, unsigned short* __restrict__ k,
    unsigned short* __restrict__ v)
{
  __shared__ __align__(16) unsigned short As[128*32];
  __shared__ __align__(16) unsigned short Bs[128*32];
  const int tid = threadIdx.x;
  const int m0 = blockIdx.y * 128, n0 = blockIdx.x * 128;
  const int wave = tid >> 6, lane = tid & 63;
  const int wm = (wave >> 1) * 64, wn = (wave & 1) * 64;
  const int lrow = lane & 15, quad = lane >> 4;

  // DMA addressing: chunk c covers rows c*16..+15, lane -> (row=c*16+(l>>2), koff=(l&3)*8)
  const int c0 = wave * 2, c1 = wave * 2 + 1;
  const int drow0 = c0*16 + (lane >> 2), drow1 = c1*16 + (lane >> 2);
  const int dkoff = (lane & 3) * 8;
  const unsigned short* ga0 = xb  + (size_t)(m0 + drow0) * D_MODEL + dkoff;
  const unsigned short* ga1 = xb  + (size_t)(m0 + drow1) * D_MODEL + dkoff;
  const unsigned short* gb0 = wqb + (size_t)(n0 + drow0) * D_MODEL + dkoff;
  const unsigned short* gb1 = wqb + (size_t)(n0 + drow1) * D_MODEL + dkoff;
  unsigned short* la0 = &As[c0*512];
  unsigned short* la1 = &As[c1*512];
  unsigned short* lb0 = &Bs[c0*512];
  unsigned short* lb1 = &Bs[c1*512];

  f32x4 acc[4][4];
  #pragma unroll
  for (int i = 0; i < 4; i++)
    #pragma unroll
    for (int j = 0; j < 4; j++) acc[i][j] = (f32x4){0.f,0.f,0.f,0.f};

  for (int k0 = 0; k0 < D_MODEL; k0 += 32) {
    __syncthreads();
    gl_lds16(ga0 + k0, la0);
    gl_lds16(ga1 + k0, la1);
    gl_lds16(gb0 + k0, lb0);
    gl_lds16(gb1 + k0, lb1);
    __syncthreads();   // vmcnt(0) drain + barrier
    bf16x8 af[4], bfr[4];
    #pragma unroll
    for (int mf = 0; mf < 4; mf++)
      af[mf] = *(const bf16x8*)&As[(wm + mf*16 + lrow)*32 + quad*8];
    #pragma unroll
    for (int nb = 0; nb < 4; nb++)
      bfr[nb] = *(const bf16x8*)&Bs[(wn + nb*16 + lrow)*32 + quad*8];
    #pragma unroll
    for (int mf = 0; mf < 4; mf++)
      #pragma unroll
      for (int nb = 0; nb < 4; nb++)
        acc[mf][nb] = __builtin_amdgcn_mfma_f32_16x16x32_bf16(af[mf], bfr[nb], acc[mf][nb], 0, 0, 0);
  }

  // epilogue: scatter q/k/v bf16 [B,NH,S,HD]; q pre-scaled by SCL2F
  #pragma unroll
  for (int mf = 0; mf < 4; mf++) {
    #pragma unroll
    for (int nb = 0; nb < 4; nb++) {
      #pragma unroll
      for (int r = 0; r < 4; r++) {
        int m = m0 + wm + mf*16 + quad*4 + r;
        int n = n0 + wn + nb*16 + lrow;
        float val = acc[mf][nb][r] + bias[n];
        int which = n >> 10;
        if (which == 0) val *= SCL2F;
        int h  = (n >> 6) & 15;
        int hd = n & 63;
        int b  = m >> 11;
        int s  = m & 2047;
        size_t idx = (size_t)((b*NHEADS + h)*SEQ + s)*HD + hd;
        unsigned short* dst = (which == 0) ? q : (which == 1) ? k : v;
        dst[idx] = f2bf(val);
      }
    }
  }
}

// ---------------- fused 3-rep causal flash attention ------------------------------
// 256-thr blocks (4 waves). Waves {0,1}=parity0 (even kt), {2,3}=parity1 (odd kt);
// wave&1 selects q-row half. Additive partial-O combine per rep (no-max softmax).
#define LDQ 72   // 144B rows, 16B-aligned, 2-way banks (free)
#define XLD 68   // exchange buffer stride (f32): breaks 16-row bank collision

__global__ __launch_bounds__(256, 4) void attn3(
    const unsigned short* __restrict__ qg,
    const unsigned short* __restrict__ kg,
    const unsigned short* __restrict__ vg,
    unsigned short* __restrict__ ctx)
{
  __shared__ __align__(16) unsigned short KQ[2][64*LDQ];
  __shared__ __align__(16) unsigned short Vt[2][64*LDQ];   // Vt[d][s] = V[s][d]

  const int tid  = threadIdx.x;
  const int w    = tid >> 6, lane = tid & 63;
  const int lrow = lane & 15, quad = lane >> 4;
  const int p    = w >> 1;        // kt parity handled by this wave
  const int sub  = w & 1;         // q-row half (sub*32..+31)
  const int bh = blockIdx.x;
  const int qt = (blockIdx.x + blockIdx.y) & 31;   // balance swizzle
  const unsigned short* qbase = qg + (size_t)bh * SEQ * HD;
  const unsigned short* kbase = kg + (size_t)bh * SEQ * HD;
  const unsigned short* vbase = vg + (size_t)bh * SEQ * HD;
  unsigned short* cbase = ctx + (size_t)bh * SEQ * HD;

  const int t128 = tid & 127;                       // within parity group
  const int srow = t128 >> 1, sc0 = (t128 & 1) * 32;      // K staging map
  const int vr0 = (t128 >> 2) * 2, vc0 = (t128 & 3) * 16; // V staging map
  const int vrot = t128 & 3;                              // write-rotation group

  // stage Q tile (rows qt*64..+63, pre-scaled) into KQ[0] with all 256 threads
  {
    int row = tid >> 2, c0q = (tid & 3) * 16;
    const unsigned short* src = qbase + (size_t)(qt*64 + row)*HD + c0q;
    *(uint4*)&KQ[0][row*LDQ + c0q]     = *(const uint4*)src;
    *(uint4*)&KQ[0][row*LDQ + c0q + 8] = *(const uint4*)(src + 8);
  }
  __syncthreads();

  // Q as K=32 B-operand frags: B[k=d=quad*8+j][n=q=lane&15]
  bf16x8 qb[2][2];
  #pragma unroll
  for (int qgi = 0; qgi < 2; qgi++) {
    qb[qgi][0] = *(const bf16x8*)&KQ[0][(sub*32 + qgi*16 + lrow)*LDQ + quad*8];
    qb[qgi][1] = *(const bf16x8*)&KQ[0][(sub*32 + qgi*16 + lrow)*LDQ + 32 + quad*8];
  }

  for (int rep = 0; rep < 3; ++rep) {
    f32x4 od[2][4];   // partial O^T[d=df*16+quad*4+r][q=lane&15]
    #pragma unroll
    for (int qgi = 0; qgi < 2; qgi++)
      #pragma unroll
      for (int df = 0; df < 4; df++) od[qgi][df] = (f32x4){0.f,0.f,0.f,0.f};
    float ls[2] = {0.f, 0.f};

    uint4 kr0, kr1, kr2, kr3, vp0, vp1, vp2, vp3;
    if (p <= qt) {   // prefetch first tile of this parity
      const unsigned short* ks = kbase + (size_t)(p*64 + srow)*HD + sc0;
      kr0 = *(const uint4*)ks;        kr1 = *(const uint4*)(ks + 8);
      kr2 = *(const uint4*)(ks + 16); kr3 = *(const uint4*)(ks + 24);
      const unsigned short* vs = vbase + (size_t)(p*64 + vr0)*HD + vc0;
      vp0 = *(const uint4*)vs;        vp1 = *(const uint4*)(vs + 8);
      vp2 = *(const uint4*)(vs + HD); vp3 = *(const uint4*)(vs + HD + 8);
    }

    const int T = (qt >> 1) + 1;   // uniform trip count for both parities
    for (int t = 0; t < T; ++t) {
      const int kt = 2*t + p;
      const bool active = (kt <= qt);
      __syncthreads();   // previous consumers of KQ[p]/Vt[p] done
      if (active) {
        *(uint4*)&KQ[p][srow*LDQ + sc0]      = kr0;
        *(uint4*)&KQ[p][srow*LDQ + sc0 + 8]  = kr1;
        *(uint4*)&KQ[p][srow*LDQ + sc0 + 16] = kr2;
        *(uint4*)&KQ[p][srow*LDQ + sc0 + 24] = kr3;
        unsigned int aw[8] = {vp0.x,vp0.y,vp0.z,vp0.w,vp1.x,vp1.y,vp1.z,vp1.w};
        unsigned int bw[8] = {vp2.x,vp2.y,vp2.z,vp2.w,vp3.x,vp3.y,vp3.z,vp3.w};
        #pragma unroll
        for (int i = 0; i < 8; i++) {
          int ii = (i + vrot) & 7;   // rotation: conflict-free write banks
          unsigned int e0 = __builtin_amdgcn_perm(bw[ii], aw[ii], 0x05040100u);
          unsigned int e1 = __builtin_amdgcn_perm(bw[ii], aw[ii], 0x07060302u);
          int col = vc0 + 2*ii;
          *(unsigned int*)&Vt[p][col*LDQ + vr0]     = e0;
          *(unsigned int*)&Vt[p][(col+1)*LDQ + vr0] = e1;
        }
      }
      if (kt + 2 <= qt) {   // prefetch next tile of this parity
        const unsigned short* ks = kbase + (size_t)((kt+2)*64 + srow)*HD + sc0;
        kr0 = *(const uint4*)ks;        kr1 = *(const uint4*)(ks + 8);
        kr2 = *(const uint4*)(ks + 16); kr3 = *(const uint4*)(ks + 24);
        const unsigned short* vs = vbase + (size_t)((kt+2)*64 + vr0)*HD + vc0;
        vp0 = *(const uint4*)vs;        vp1 = *(const uint4*)(vs + 8);
        vp2 = *(const uint4*)(vs + HD); vp3 = *(const uint4*)(vs + HD + 8);
      }
      __syncthreads();
      if (active) {
        // scores: S^T = K * Q^T (K=32 MFMA), A-frags shared across q-groups
        f32x4 sc[2][4];
        #pragma unroll
        for (int sf = 0; sf < 4; sf++) {
          bf16x8 a0 = *(const bf16x8*)&KQ[p][(sf*16 + lrow)*LDQ + quad*8];
          bf16x8 a1 = *(const bf16x8*)&KQ[p][(sf*16 + lrow)*LDQ + 32 + quad*8];
          f32x4 z0 = (f32x4){0.f,0.f,0.f,0.f}, z1 = z0;
          z0 = __builtin_amdgcn_mfma_f32_16x16x32_bf16(a0, qb[0][0], z0, 0, 0, 0);
          z1 = __builtin_amdgcn_mfma_f32_16x16x32_bf16(a0, qb[1][0], z1, 0, 0, 0);
          z0 = __builtin_amdgcn_mfma_f32_16x16x32_bf16(a1, qb[0][1], z0, 0, 0, 0);
          z1 = __builtin_amdgcn_mfma_f32_16x16x32_bf16(a1, qb[1][1], z1, 0, 0, 0);
          sc[0][sf] = z0; sc[1][sf] = z1;
        }
        if (kt == qt) {   // causal mask, exp2 domain
          #pragma unroll
          for (int qgi = 0; qgi < 2; qgi++) {
            int ql = sub*32 + qgi*16 + lrow;
            #pragma unroll
            for (int sf = 0; sf < 4; sf++)
              #pragma unroll
              for (int r = 0; r < 4; r++)
                if (sf*16 + quad*4 + r > ql) sc[qgi][sf][r] += MASK2;
          }
        }
        // p = exp2(s) (bounded scores); P lands in K=16 B-layout
        s16x4 pf[2][4];
        #pragma unroll
        for (int qgi = 0; qgi < 2; qgi++) {
          float lp = 0.f;
          #pragma unroll
          for (int sf = 0; sf < 4; sf++) {
            union { s16x4 v; unsigned short e[4]; } pk;
            #pragma unroll
            for (int r = 0; r < 4; r++) {
              float pe = exp2f(sc[qgi][sf][r]);
              lp += pe;
              pk.e[r] = __builtin_bit_cast(unsigned short, (__bf16)pe);
            }
            pf[qgi][sf] = pk.v;
          }
          ls[qgi] += lp;
        }
        // PV: O^T += V^T * P^T (K=16), A-frags shared across q-groups
        #pragma unroll
        for (int df = 0; df < 4; df++) {
          s16x4 v0 = *(const s16x4*)&Vt[p][(df*16 + lrow)*LDQ +  0 + quad*4];
          s16x4 v1 = *(const s16x4*)&Vt[p][(df*16 + lrow)*LDQ + 16 + quad*4];
          s16x4 v2 = *(const s16x4*)&Vt[p][(df*16 + lrow)*LDQ + 32 + quad*4];
          s16x4 v3 = *(const s16x4*)&Vt[p][(df*16 + lrow)*LDQ + 48 + quad*4];
          od[0][df] = __builtin_amdgcn_mfma_f32_16x16x16bf16_1k(v0, pf[0][0], od[0][df], 0, 0, 0);
          od[1][df] = __builtin_amdgcn_mfma_f32_16x16x16bf16_1k(v0, pf[1][0], od[1][df], 0, 0, 0);
          od[0][df] = __builtin_amdgcn_mfma_f32_16x16x16bf16_1k(v1, pf[0][1], od[0][df], 0, 0, 0);
          od[1][df] = __builtin_amdgcn_mfma_f32_16x16x16bf16_1k(v1, pf[1][1], od[1][df], 0, 0, 0);
          od[0][df] = __builtin_amdgcn_mfma_f32_16x16x16bf16_1k(v2, pf[0][2], od[0][df], 0, 0, 0);
          od[1][df] = __builtin_amdgcn_mfma_f32_16x16x16bf16_1k(v2, pf[1][2], od[1][df], 0, 0, 0);
          od[0][df] = __builtin_amdgcn_mfma_f32_16x16x16bf16_1k(v3, pf[0][3], od[0][df], 0, 0, 0);
          od[1][df] = __builtin_amdgcn_mfma_f32_16x16x16bf16_1k(v3, pf[1][3], od[1][df], 0, 0, 0);
        }
      }
    } // t

    // reduce partial l across quads (q id depends only on lane&15)
    #pragma unroll
    for (int qgi = 0; qgi < 2; qgi++) {
      ls[qgi] += __shfl_xor(ls[qgi], 16);
      ls[qgi] += __shfl_xor(ls[qgi], 32);
    }

    __syncthreads();   // all KQ/Vt reads done; repurpose KQ[1]/Vt[1] as exchange
    float* xch = (sub == 0) ? (float*)&KQ[1][0] : (float*)&Vt[1][0];
    if (p == 1) {      // parity-1 waves export partial O and l
      #pragma unroll
      for (int qgi = 0; qgi < 2; qgi++) {
        #pragma unroll
        for (int df = 0; df < 4; df++)
          *(f32x4*)&xch[(qgi*16 + lrow)*XLD + df*16 + quad*4] = od[qgi][df];
        if (quad == 0) xch[32*XLD + qgi*16 + lrow] = ls[qgi];
      }
    }
    __syncthreads();
    if (p == 0) {      // parity-0 waves combine, normalize, write new Q / output
      #pragma unroll
      for (int qgi = 0; qgi < 2; qgi++) {
        float ltot = ls[qgi] + xch[32*XLD + qgi*16 + lrow];
        float f = ((rep < 2) ? SCL2F : 1.0f) / ltot;
        #pragma unroll
        for (int df = 0; df < 4; df++) {
          f32x4 part = *(const f32x4*)&xch[(qgi*16 + lrow)*XLD + df*16 + quad*4];
          union { s16x4 v; unsigned short e[4]; } pk;
          #pragma unroll
          for (int r = 0; r < 4; r++)
            pk.e[r] = __builtin_bit_cast(unsigned short,
                        (__bf16)((od[qgi][df][r] + part[r]) * f));
          *(s16x4*)&KQ[0][(sub*32 + qgi*16 + lrow)*LDQ + df*16 + quad*4] = pk.v;
        }
      }
    }
    __syncthreads();
    if (rep < 2) {     // all waves reload chained Q frags
      #pragma unroll
      for (int qgi = 0; qgi < 2; qgi++) {
        qb[qgi][0] = *(const bf16x8*)&KQ[0][(sub*32 + qgi*16 + lrow)*LDQ + quad*8];
        qb[qgi][1] = *(const bf16x8*)&KQ[0][(sub*32 + qgi*16 + lrow)*LDQ + 32 + quad*8];
      }
    }
  } // rep

  {   // coalesced ctx store from KQ[0]
    int row = tid >> 2, c0q = (tid & 3) * 16;
    unsigned short* dst = cbase + (size_t)(qt*64 + row)*HD + c0q;
    *(uint4*)dst       = *(const uint4*)&KQ[0][row*LDQ + c0q];
    *(uint4*)(dst + 8) = *(const uint4*)&KQ[0][row*LDQ + c0q + 8];
  }
}

// ---------------- out projection: 128x64x32 tiles, async staging, fp32 out -------
__global__ __launch_bounds__(256) void out_gemm(
    const unsigned short* __restrict__ ctx, const unsigned short* __restrict__ owb,
    const float* __restrict__ bias, float* __restrict__ out)
{
  __shared__ __align__(16) unsigned short As[128*32];
  __shared__ __align__(16) unsigned short Bs[64*32];
  const int tid = threadIdx.x;
  const int m0 = blockIdx.y * 128, n0 = blockIdx.x * 64;
  const int wave = tid >> 6, lane = tid & 63;
  const int wm = (wave >> 1) * 64, wn = (wave & 1) * 32;
  const int lrow = lane & 15, quad = lane >> 4;

  // DMA: A chunks {wave, wave+4}, B chunk {wave}
  const int dl = lane >> 2, dkoff = (lane & 3) * 8;
  const int ar0 = wave*16 + dl, ar1 = (wave+4)*16 + dl;
  // A gather rows: m -> (b,s); k -> (h,hd)
  const int am0 = m0 + ar0, am1 = m0 + ar1;
  const size_t abase0 = ((size_t)((am0 >> 11)*NHEADS)*SEQ + (am0 & 2047))*HD;
  const size_t abase1 = ((size_t)((am1 >> 11)*NHEADS)*SEQ + (am1 & 2047))*HD;
  const unsigned short* gb = owb + (size_t)(n0 + wave*16 + dl) * D_MODEL + dkoff;
  unsigned short* la0 = &As[wave*512];
  unsigned short* la1 = &As[(wave+4)*512];
  unsigned short* lb  = &Bs[wave*512];

  f32x4 acc[4][2];
  #pragma unroll
  for (int i = 0; i < 4; i++)
    #pragma unroll
    for (int j = 0; j < 2; j++) acc[i][j] = (f32x4){0.f,0.f,0.f,0.f};

  for (int k0 = 0; k0 < D_MODEL; k0 += 32) {
    int kk = k0 + dkoff;
    int h = kk >> 6, hd = kk & 63;
    size_t hoff = (size_t)h * SEQ * HD + hd;
    __syncthreads();
    gl_lds16(ctx + abase0 + hoff, la0);
    gl_lds16(ctx + abase1 + hoff, la1);
    gl_lds16(gb + k0, lb);
    __syncthreads();
    bf16x8 af[4], bfr[2];
    #pragma unroll
    for (int mf = 0; mf < 4; mf++)
      af[mf] = *(const bf16x8*)&As[(wm + mf*16 + lrow)*32 + quad*8];
    #pragma unroll
    for (int nb = 0; nb < 2; nb++)
      bfr[nb] = *(const bf16x8*)&Bs[(wn + nb*16 + lrow)*32 + quad*8];
    #pragma unroll
    for (int mf = 0; mf < 4; mf++)
      #pragma unroll
      for (int nb = 0; nb < 2; nb++)
        acc[mf][nb] = __builtin_amdgcn_mfma_f32_16x16x32_bf16(af[mf], bfr[nb], acc[mf][nb], 0, 0, 0);
  }

  #pragma unroll
  for (int mf = 0; mf < 4; mf++) {
    #pragma unroll
    for (int nb = 0; nb < 2; nb++) {
      #pragma unroll
      for (int r = 0; r < 4; r++) {
        int mm = m0 + wm + mf*16 + quad*4 + r;
        int n  = n0 + wn + nb*16 + lrow;
        out[(size_t)mm * D_MODEL + n] = acc[mf][nb][r] + bias[n];
      }
    }
  }
}

extern "C" void kernel_launch(void* const* d_in, const int* in_sizes, int n_in,
                              void* d_out, int out_size, void* d_ws, size_t ws_size,
                              hipStream_t stream) {
  (void)in_sizes; (void)n_in; (void)out_size; (void)ws_size;
  const float* x      = (const float*)d_in[0];
  const float* Wqkv_w = (const float*)d_in[1];
  const float* Wqkv_b = (const float*)d_in[2];
  const float* out_w  = (const float*)d_in[3];
  const float* out_b  = (const float*)d_in[4];
  float* out = (float*)d_out;

  unsigned short* ws = (unsigned short*)d_ws;
  unsigned short* xb  = ws;                              // 4.19M elems; reused as ctx
  unsigned short* wqb = ws + CVT_N1;                     // 3.15M
  unsigned short* owb = ws + CVT_N1 + CVT_N2;            // 1.05M
  unsigned short* q   = ws + CVT_N1 + CVT_N2 + CVT_N3;   // 4.19M each
  unsigned short* k   = q + (size_t)NROWS*D_MODEL;
  unsigned short* v   = k + (size_t)NROWS*D_MODEL;
  unsigned short* ctx = xb;                              // alias: xb dead after qkv

  cvt_all<<<(CVT_N1+CVT_N2+CVT_N3)/(256*8), 256, 0, stream>>>(x, Wqkv_w, out_w, xb, wqb, owb);
  qkv_gemm<<<dim3(NQKV/128, NROWS/128), 256, 0, stream>>>(xb, wqb, Wqkv_b, q, k, v);
  attn3<<<dim3(BATCH*NHEADS, SEQ/64), 256, 0, stream>>>(q, k, v, ctx);
  out_gemm<<<dim3(D_MODEL/64, NROWS/128), 256, 0, stream>>>(ctx, owb, out_b, out);
}

// Round 5
// 350.400 us; speedup vs baseline: 1.7732x; 1.7732x over previous
//
#include <hip/hip_runtime.h>

// MHR_76965813945133: x->QKV proj -> 3x causal MHA (Q<-ctx, K/V fixed) -> out proj.
// B=2, S=2048, D=1024, NH=16, HD=64. bf16 MFMA compute, fp32 accum.
// R5: R4 minus the spill: attn3 __launch_bounds__(256) WITHOUT min-waves arg.
//     R4's (256,4) capped VGPRs at 64 -> ~560MB scratch spill traffic (WRITE_SIZE).
//     Everything else (parity-split kt, V-rotation, global_load_lds GEMMs) kept.

#define D_MODEL 1024
#define NHEADS  16
#define HD      64
#define SEQ     2048
#define BATCH   2
#define NROWS   (BATCH*SEQ)   // 4096
#define NQKV    (3*D_MODEL)   // 3072
#define SCL2F   0.1803368801111601f      // 0.125 * log2(e)
#define MASK2   (-14426.950408889634f)   // -10000 * log2(e)

typedef __bf16 bf16x8 __attribute__((ext_vector_type(8)));
typedef float  f32x4  __attribute__((ext_vector_type(4)));
typedef unsigned short us8 __attribute__((ext_vector_type(8)));
typedef short  s16x4  __attribute__((ext_vector_type(4)));

__device__ __forceinline__ unsigned short f2bf(float f) {
  unsigned int u = __float_as_uint(f);
  u = (u + 0x7fffu + ((u >> 16) & 1u)) >> 16;   // RNE
  return (unsigned short)u;
}

union Pack8 { us8 v; unsigned short e[8]; };

__device__ __forceinline__ us8 cvt8(const float4 &a, const float4 &b) {
  Pack8 p;
  p.e[0]=f2bf(a.x); p.e[1]=f2bf(a.y); p.e[2]=f2bf(a.z); p.e[3]=f2bf(a.w);
  p.e[4]=f2bf(b.x); p.e[5]=f2bf(b.y); p.e[6]=f2bf(b.z); p.e[7]=f2bf(b.w);
  return p.v;
}

__device__ __forceinline__ void gl_lds16(const unsigned short* g, unsigned short* l) {
  __builtin_amdgcn_global_load_lds(
      (const __attribute__((address_space(1))) unsigned int*)g,
      (__attribute__((address_space(3))) unsigned int*)l, 16, 0, 0);
}

// ---------------- fp32 -> bf16 pre-convert (x, Wqkv_w, out_w) --------------------
#define CVT_N1 (NROWS*D_MODEL)    // 4194304
#define CVT_N2 (NQKV*D_MODEL)     // 3145728
#define CVT_N3 (D_MODEL*D_MODEL)  // 1048576

__global__ __launch_bounds__(256) void cvt_all(
    const float* __restrict__ x, const float* __restrict__ wq,
    const float* __restrict__ ow,
    unsigned short* __restrict__ xb, unsigned short* __restrict__ wqb,
    unsigned short* __restrict__ owb)
{
  size_t i = ((size_t)blockIdx.x * 256 + threadIdx.x) * 8;
  const float* src; unsigned short* dst; size_t off;
  if (i < CVT_N1)                { src = x;  dst = xb;  off = i; }
  else if (i < CVT_N1 + CVT_N2)  { src = wq; dst = wqb; off = i - CVT_N1; }
  else                           { src = ow; dst = owb; off = i - CVT_N1 - CVT_N2; }
  float4 a = *(const float4*)(src + off);
  float4 b = *(const float4*)(src + off + 4);
  *(us8*)(dst + off) = cvt8(a, b);
}

// ---------------- QKV GEMM: bf16, m97-style async staging ------------------------
// 128x128x32 tiles, 4 waves (2x2), 4x4 frags. As/Bs unpadded (DMA layout).
__global__ __launch_bounds__(256) void qkv_gemm(
    const unsigned short* __restrict__ xb, const unsigned short* __restrict__ wqb,
    const float* __restrict__ bias,
    unsigned short* __restrict__ q, unsigned short* __restrict__ k,
    unsigned short* __restrict__ v)
{
  __shared__ __align__(16) unsigned short As[128*32];
  __shared__ __align__(16) unsigned short Bs[128*32];
  const int tid = threadIdx.x;
  const int m0 = blockIdx.y * 128, n0 = blockIdx.x * 128;
  const int wave = tid >> 6, lane = tid & 63;
  const int wm = (wave >> 1) * 64, wn = (wave & 1) * 64;
  const int lrow = lane & 15, quad = lane >> 4;

  // DMA addressing: chunk c covers rows c*16..+15, lane -> (row=c*16+(l>>2), koff=(l&3)*8)
  const int c0 = wave * 2, c1 = wave * 2 + 1;
  const int drow0 = c0*16 + (lane >> 2), drow1 = c1*16 + (lane >> 2);
  const int dkoff = (lane & 3) * 8;
  const unsigned short* ga0 = xb  + (size_t)(m0 + drow0) * D_MODEL + dkoff;
  const unsigned short* ga1 = xb  + (size_t)(m0 + drow1) * D_MODEL + dkoff;
  const unsigned short* gb0 = wqb + (size_t)(n0 + drow0) * D_MODEL + dkoff;
  const unsigned short* gb1 = wqb + (size_t)(n0 + drow1) * D_MODEL + dkoff;
  unsigned short* la0 = &As[c0*512];
  unsigned short* la1 = &As[c1*512];
  unsigned short* lb0 = &Bs[c0*512];
  unsigned short* lb1 = &Bs[c1*512];

  f32x4 acc[4][4];
  #pragma unroll
  for (int i = 0; i < 4; i++)
    #pragma unroll
    for (int j = 0; j < 4; j++) acc[i][j] = (f32x4){0.f,0.f,0.f,0.f};

  for (int k0 = 0; k0 < D_MODEL; k0 += 32) {
    __syncthreads();
    gl_lds16(ga0 + k0, la0);
    gl_lds16(ga1 + k0, la1);
    gl_lds16(gb0 + k0, lb0);
    gl_lds16(gb1 + k0, lb1);
    __syncthreads();   // vmcnt(0) drain + barrier
    bf16x8 af[4], bfr[4];
    #pragma unroll
    for (int mf = 0; mf < 4; mf++)
      af[mf] = *(const bf16x8*)&As[(wm + mf*16 + lrow)*32 + quad*8];
    #pragma unroll
    for (int nb = 0; nb < 4; nb++)
      bfr[nb] = *(const bf16x8*)&Bs[(wn + nb*16 + lrow)*32 + quad*8];
    #pragma unroll
    for (int mf = 0; mf < 4; mf++)
      #pragma unroll
      for (int nb = 0; nb < 4; nb++)
        acc[mf][nb] = __builtin_amdgcn_mfma_f32_16x16x32_bf16(af[mf], bfr[nb], acc[mf][nb], 0, 0, 0);
  }

  // epilogue: scatter q/k/v bf16 [B,NH,S,HD]; q pre-scaled by SCL2F
  #pragma unroll
  for (int mf = 0; mf < 4; mf++) {
    #pragma unroll
    for (int nb = 0; nb < 4; nb++) {
      #pragma unroll
      for (int r = 0; r < 4; r++) {
        int m = m0 + wm + mf*16 + quad*4 + r;
        int n = n0 + wn + nb*16 + lrow;
        float val = acc[mf][nb][r] + bias[n];
        int which = n >> 10;
        if (which == 0) val *= SCL2F;
        int h  = (n >> 6) & 15;
        int hd = n & 63;
        int b  = m >> 11;
        int s  = m & 2047;
        size_t idx = (size_t)((b*NHEADS + h)*SEQ + s)*HD + hd;
        unsigned short* dst = (which == 0) ? q : (which == 1) ? k : v;
        dst[idx] = f2bf(val);
      }
    }
  }
}

// ---------------- fused 3-rep causal flash attention ------------------------------
// 256-thr blocks (4 waves). Waves {0,1}=parity0 (even kt), {2,3}=parity1 (odd kt);
// wave&1 selects q-row half. Additive partial-O combine per rep (no-max softmax).
#define LDQ 72   // 144B rows, 16B-aligned, 2-way banks (free)
#define XLD 68   // exchange buffer stride (f32): breaks 16-row bank collision

__global__ __launch_bounds__(256) void attn3(
    const unsigned short* __restrict__ qg,
    const unsigned short* __restrict__ kg,
    const unsigned short* __restrict__ vg,
    unsigned short* __restrict__ ctx)
{
  __shared__ __align__(16) unsigned short KQ[2][64*LDQ];
  __shared__ __align__(16) unsigned short Vt[2][64*LDQ];   // Vt[d][s] = V[s][d]

  const int tid  = threadIdx.x;
  const int w    = tid >> 6, lane = tid & 63;
  const int lrow = lane & 15, quad = lane >> 4;
  const int p    = w >> 1;        // kt parity handled by this wave
  const int sub  = w & 1;         // q-row half (sub*32..+31)
  const int bh = blockIdx.x;
  const int qt = (blockIdx.x + blockIdx.y) & 31;   // balance swizzle
  const unsigned short* qbase = qg + (size_t)bh * SEQ * HD;
  const unsigned short* kbase = kg + (size_t)bh * SEQ * HD;
  const unsigned short* vbase = vg + (size_t)bh * SEQ * HD;
  unsigned short* cbase = ctx + (size_t)bh * SEQ * HD;

  const int t128 = tid & 127;                       // within parity group
  const int srow = t128 >> 1, sc0 = (t128 & 1) * 32;      // K staging map
  const int vr0 = (t128 >> 2) * 2, vc0 = (t128 & 3) * 16; // V staging map
  const int vrot = t128 & 3;                              // write-rotation group

  // stage Q tile (rows qt*64..+63, pre-scaled) into KQ[0] with all 256 threads
  {
    int row = tid >> 2, c0q = (tid & 3) * 16;
    const unsigned short* src = qbase + (size_t)(qt*64 + row)*HD + c0q;
    *(uint4*)&KQ[0][row*LDQ + c0q]     = *(const uint4*)src;
    *(uint4*)&KQ[0][row*LDQ + c0q + 8] = *(const uint4*)(src + 8);
  }
  __syncthreads();

  // Q as K=32 B-operand frags: B[k=d=quad*8+j][n=q=lane&15]
  bf16x8 qb[2][2];
  #pragma unroll
  for (int qgi = 0; qgi < 2; qgi++) {
    qb[qgi][0] = *(const bf16x8*)&KQ[0][(sub*32 + qgi*16 + lrow)*LDQ + quad*8];
    qb[qgi][1] = *(const bf16x8*)&KQ[0][(sub*32 + qgi*16 + lrow)*LDQ + 32 + quad*8];
  }

  for (int rep = 0; rep < 3; ++rep) {
    f32x4 od[2][4];   // partial O^T[d=df*16+quad*4+r][q=lane&15]
    #pragma unroll
    for (int qgi = 0; qgi < 2; qgi++)
      #pragma unroll
      for (int df = 0; df < 4; df++) od[qgi][df] = (f32x4){0.f,0.f,0.f,0.f};
    float ls[2] = {0.f, 0.f};

    uint4 kr0, kr1, kr2, kr3, vp0, vp1, vp2, vp3;
    if (p <= qt) {   // prefetch first tile of this parity
      const unsigned short* ks = kbase + (size_t)(p*64 + srow)*HD + sc0;
      kr0 = *(const uint4*)ks;        kr1 = *(const uint4*)(ks + 8);
      kr2 = *(const uint4*)(ks + 16); kr3 = *(const uint4*)(ks + 24);
      const unsigned short* vs = vbase + (size_t)(p*64 + vr0)*HD + vc0;
      vp0 = *(const uint4*)vs;        vp1 = *(const uint4*)(vs + 8);
      vp2 = *(const uint4*)(vs + HD); vp3 = *(const uint4*)(vs + HD + 8);
    }

    const int T = (qt >> 1) + 1;   // uniform trip count for both parities
    for (int t = 0; t < T; ++t) {
      const int kt = 2*t + p;
      const bool active = (kt <= qt);
      __syncthreads();   // previous consumers of KQ[p]/Vt[p] done
      if (active) {
        *(uint4*)&KQ[p][srow*LDQ + sc0]      = kr0;
        *(uint4*)&KQ[p][srow*LDQ + sc0 + 8]  = kr1;
        *(uint4*)&KQ[p][srow*LDQ + sc0 + 16] = kr2;
        *(uint4*)&KQ[p][srow*LDQ + sc0 + 24] = kr3;
        unsigned int aw[8] = {vp0.x,vp0.y,vp0.z,vp0.w,vp1.x,vp1.y,vp1.z,vp1.w};
        unsigned int bw[8] = {vp2.x,vp2.y,vp2.z,vp2.w,vp3.x,vp3.y,vp3.z,vp3.w};
        #pragma unroll
        for (int i = 0; i < 8; i++) {
          int ii = (i + vrot) & 7;   // rotation: conflict-free write banks
          unsigned int e0 = __builtin_amdgcn_perm(bw[ii], aw[ii], 0x05040100u);
          unsigned int e1 = __builtin_amdgcn_perm(bw[ii], aw[ii], 0x07060302u);
          int col = vc0 + 2*ii;
          *(unsigned int*)&Vt[p][col*LDQ + vr0]     = e0;
          *(unsigned int*)&Vt[p][(col+1)*LDQ + vr0] = e1;
        }
      }
      if (kt + 2 <= qt) {   // prefetch next tile of this parity
        const unsigned short* ks = kbase + (size_t)((kt+2)*64 + srow)*HD + sc0;
        kr0 = *(const uint4*)ks;        kr1 = *(const uint4*)(ks + 8);
        kr2 = *(const uint4*)(ks + 16); kr3 = *(const uint4*)(ks + 24);
        const unsigned short* vs = vbase + (size_t)((kt+2)*64 + vr0)*HD + vc0;
        vp0 = *(const uint4*)vs;        vp1 = *(const uint4*)(vs + 8);
        vp2 = *(const uint4*)(vs + HD); vp3 = *(const uint4*)(vs + HD + 8);
      }
      __syncthreads();
      if (active) {
        // scores: S^T = K * Q^T (K=32 MFMA), A-frags shared across q-groups
        f32x4 sc[2][4];
        #pragma unroll
        for (int sf = 0; sf < 4; sf++) {
          bf16x8 a0 = *(const bf16x8*)&KQ[p][(sf*16 + lrow)*LDQ + quad*8];
          bf16x8 a1 = *(const bf16x8*)&KQ[p][(sf*16 + lrow)*LDQ + 32 + quad*8];
          f32x4 z0 = (f32x4){0.f,0.f,0.f,0.f}, z1 = z0;
          z0 = __builtin_amdgcn_mfma_f32_16x16x32_bf16(a0, qb[0][0], z0, 0, 0, 0);
          z1 = __builtin_amdgcn_mfma_f32_16x16x32_bf16(a0, qb[1][0], z1, 0, 0, 0);
          z0 = __builtin_amdgcn_mfma_f32_16x16x32_bf16(a1, qb[0][1], z0, 0, 0, 0);
          z1 = __builtin_amdgcn_mfma_f32_16x16x32_bf16(a1, qb[1][1], z1, 0, 0, 0);
          sc[0][sf] = z0; sc[1][sf] = z1;
        }
        if (kt == qt) {   // causal mask, exp2 domain
          #pragma unroll
          for (int qgi = 0; qgi < 2; qgi++) {
            int ql = sub*32 + qgi*16 + lrow;
            #pragma unroll
            for (int sf = 0; sf < 4; sf++)
              #pragma unroll
              for (int r = 0; r < 4; r++)
                if (sf*16 + quad*4 + r > ql) sc[qgi][sf][r] += MASK2;
          }
        }
        // p = exp2(s) (bounded scores); P lands in K=16 B-layout
        s16x4 pf[2][4];
        #pragma unroll
        for (int qgi = 0; qgi < 2; qgi++) {
          float lp = 0.f;
          #pragma unroll
          for (int sf = 0; sf < 4; sf++) {
            union { s16x4 v; unsigned short e[4]; } pk;
            #pragma unroll
            for (int r = 0; r < 4; r++) {
              float pe = exp2f(sc[qgi][sf][r]);
              lp += pe;
              pk.e[r] = __builtin_bit_cast(unsigned short, (__bf16)pe);
            }
            pf[qgi][sf] = pk.v;
          }
          ls[qgi] += lp;
        }
        // PV: O^T += V^T * P^T (K=16), A-frags shared across q-groups
        #pragma unroll
        for (int df = 0; df < 4; df++) {
          s16x4 v0 = *(const s16x4*)&Vt[p][(df*16 + lrow)*LDQ +  0 + quad*4];
          s16x4 v1 = *(const s16x4*)&Vt[p][(df*16 + lrow)*LDQ + 16 + quad*4];
          s16x4 v2 = *(const s16x4*)&Vt[p][(df*16 + lrow)*LDQ + 32 + quad*4];
          s16x4 v3 = *(const s16x4*)&Vt[p][(df*16 + lrow)*LDQ + 48 + quad*4];
          od[0][df] = __builtin_amdgcn_mfma_f32_16x16x16bf16_1k(v0, pf[0][0], od[0][df], 0, 0, 0);
          od[1][df] = __builtin_amdgcn_mfma_f32_16x16x16bf16_1k(v0, pf[1][0], od[1][df], 0, 0, 0);
          od[0][df] = __builtin_amdgcn_mfma_f32_16x16x16bf16_1k(v1, pf[0][1], od[0][df], 0, 0, 0);
          od[1][df] = __builtin_amdgcn_mfma_f32_16x16x16bf16_1k(v1, pf[1][1], od[1][df], 0, 0, 0);
          od[0][df] = __builtin_amdgcn_mfma_f32_16x16x16bf16_1k(v2, pf[0][2], od[0][df], 0, 0, 0);
          od[1][df] = __builtin_amdgcn_mfma_f32_16x16x16bf16_1k(v2, pf[1][2], od[1][df], 0, 0, 0);
          od[0][df] = __builtin_amdgcn_mfma_f32_16x16x16bf16_1k(v3, pf[0][3], od[0][df], 0, 0, 0);
          od[1][df] = __builtin_amdgcn_mfma_f32_16x16x16bf16_1k(v3, pf[1][3], od[1][df], 0, 0, 0);
        }
      }
    } // t

    // reduce partial l across quads (q id depends only on lane&15)
    #pragma unroll
    for (int qgi = 0; qgi < 2; qgi++) {
      ls[qgi] += __shfl_xor(ls[qgi], 16);
      ls[qgi] += __shfl_xor(ls[qgi], 32);
    }

    __syncthreads();   // all KQ/Vt reads done; repurpose KQ[1]/Vt[1] as exchange
    float* xch = (sub == 0) ? (float*)&KQ[1][0] : (float*)&Vt[1][0];
    if (p == 1) {      // parity-1 waves export partial O and l
      #pragma unroll
      for (int qgi = 0; qgi < 2; qgi++) {
        #pragma unroll
        for (int df = 0; df < 4; df++)
          *(f32x4*)&xch[(qgi*16 + lrow)*XLD + df*16 + quad*4] = od[qgi][df];
        if (quad == 0) xch[32*XLD + qgi*16 + lrow] = ls[qgi];
      }
    }
    __syncthreads();
    if (p == 0) {      // parity-0 waves combine, normalize, write new Q / output
      #pragma unroll
      for (int qgi = 0; qgi < 2; qgi++) {
        float ltot = ls[qgi] + xch[32*XLD + qgi*16 + lrow];
        float f = ((rep < 2) ? SCL2F : 1.0f) / ltot;
        #pragma unroll
        for (int df = 0; df < 4; df++) {
          f32x4 part = *(const f32x4*)&xch[(qgi*16 + lrow)*XLD + df*16 + quad*4];
          union { s16x4 v; unsigned short e[4]; } pk;
          #pragma unroll
          for (int r = 0; r < 4; r++)
            pk.e[r] = __builtin_bit_cast(unsigned short,
                        (__bf16)((od[qgi][df][r] + part[r]) * f));
          *(s16x4*)&KQ[0][(sub*32 + qgi*16 + lrow)*LDQ + df*16 + quad*4] = pk.v;
        }
      }
    }
    __syncthreads();
    if (rep < 2) {     // all waves reload chained Q frags
      #pragma unroll
      for (int qgi = 0; qgi < 2; qgi++) {
        qb[qgi][0] = *(const bf16x8*)&KQ[0][(sub*32 + qgi*16 + lrow)*LDQ + quad*8];
        qb[qgi][1] = *(const bf16x8*)&KQ[0][(sub*32 + qgi*16 + lrow)*LDQ + 32 + quad*8];
      }
    }
  } // rep

  {   // coalesced ctx store from KQ[0]
    int row = tid >> 2, c0q = (tid & 3) * 16;
    unsigned short* dst = cbase + (size_t)(qt*64 + row)*HD + c0q;
    *(uint4*)dst       = *(const uint4*)&KQ[0][row*LDQ + c0q];
    *(uint4*)(dst + 8) = *(const uint4*)&KQ[0][row*LDQ + c0q + 8];
  }
}

// ---------------- out projection: 128x64x32 tiles, async staging, fp32 out -------
__global__ __launch_bounds__(256) void out_gemm(
    const unsigned short* __restrict__ ctx, const unsigned short* __restrict__ owb,
    const float* __restrict__ bias, float* __restrict__ out)
{
  __shared__ __align__(16) unsigned short As[128*32];
  __shared__ __align__(16) unsigned short Bs[64*32];
  const int tid = threadIdx.x;
  const int m0 = blockIdx.y * 128, n0 = blockIdx.x * 64;
  const int wave = tid >> 6, lane = tid & 63;
  const int wm = (wave >> 1) * 64, wn = (wave & 1) * 32;
  const int lrow = lane & 15, quad = lane >> 4;

  // DMA: A chunks {wave, wave+4}, B chunk {wave}
  const int dl = lane >> 2, dkoff = (lane & 3) * 8;
  const int ar0 = wave*16 + dl, ar1 = (wave+4)*16 + dl;
  // A gather rows: m -> (b,s); k -> (h,hd)
  const int am0 = m0 + ar0, am1 = m0 + ar1;
  const size_t abase0 = ((size_t)((am0 >> 11)*NHEADS)*SEQ + (am0 & 2047))*HD;
  const size_t abase1 = ((size_t)((am1 >> 11)*NHEADS)*SEQ + (am1 & 2047))*HD;
  const unsigned short* gb = owb + (size_t)(n0 + wave*16 + dl) * D_MODEL + dkoff;
  unsigned short* la0 = &As[wave*512];
  unsigned short* la1 = &As[(wave+4)*512];
  unsigned short* lb  = &Bs[wave*512];

  f32x4 acc[4][2];
  #pragma unroll
  for (int i = 0; i < 4; i++)
    #pragma unroll
    for (int j = 0; j < 2; j++) acc[i][j] = (f32x4){0.f,0.f,0.f,0.f};

  for (int k0 = 0; k0 < D_MODEL; k0 += 32) {
    int kk = k0 + dkoff;
    int h = kk >> 6, hd = kk & 63;
    size_t hoff = (size_t)h * SEQ * HD + hd;
    __syncthreads();
    gl_lds16(ctx + abase0 + hoff, la0);
    gl_lds16(ctx + abase1 + hoff, la1);
    gl_lds16(gb + k0, lb);
    __syncthreads();
    bf16x8 af[4], bfr[2];
    #pragma unroll
    for (int mf = 0; mf < 4; mf++)
      af[mf] = *(const bf16x8*)&As[(wm + mf*16 + lrow)*32 + quad*8];
    #pragma unroll
    for (int nb = 0; nb < 2; nb++)
      bfr[nb] = *(const bf16x8*)&Bs[(wn + nb*16 + lrow)*32 + quad*8];
    #pragma unroll
    for (int mf = 0; mf < 4; mf++)
      #pragma unroll
      for (int nb = 0; nb < 2; nb++)
        acc[mf][nb] = __builtin_amdgcn_mfma_f32_16x16x32_bf16(af[mf], bfr[nb], acc[mf][nb], 0, 0, 0);
  }

  #pragma unroll
  for (int mf = 0; mf < 4; mf++) {
    #pragma unroll
    for (int nb = 0; nb < 2; nb++) {
      #pragma unroll
      for (int r = 0; r < 4; r++) {
        int mm = m0 + wm + mf*16 + quad*4 + r;
        int n  = n0 + wn + nb*16 + lrow;
        out[(size_t)mm * D_MODEL + n] = acc[mf][nb][r] + bias[n];
      }
    }
  }
}

extern "C" void kernel_launch(void* const* d_in, const int* in_sizes, int n_in,
                              void* d_out, int out_size, void* d_ws, size_t ws_size,
                              hipStream_t stream) {
  (void)in_sizes; (void)n_in; (void)out_size; (void)ws_size;
  const float* x      = (const float*)d_in[0];
  const float* Wqkv_w = (const float*)d_in[1];
  const float* Wqkv_b = (const float*)d_in[2];
  const float* out_w  = (const float*)d_in[3];
  const float* out_b  = (const float*)d_in[4];
  float* out = (float*)d_out;

  unsigned short* ws = (unsigned short*)d_ws;
  unsigned short* xb  = ws;                              // 4.19M elems; reused as ctx
  unsigned short* wqb = ws + CVT_N1;                     // 3.15M
  unsigned short* owb = ws + CVT_N1 + CVT_N2;            // 1.05M
  unsigned short* q   = ws + CVT_N1 + CVT_N2 + CVT_N3;   // 4.19M each
  unsigned short* k   = q + (size_t)NROWS*D_MODEL;
  unsigned short* v   = k + (size_t)NROWS*D_MODEL;
  unsigned short* ctx = xb;                              // alias: xb dead after qkv

  cvt_all<<<(CVT_N1+CVT_N2+CVT_N3)/(256*8), 256, 0, stream>>>(x, Wqkv_w, out_w, xb, wqb, owb);
  qkv_gemm<<<dim3(NQKV/128, NROWS/128), 256, 0, stream>>>(xb, wqb, Wqkv_b, q, k, v);
  attn3<<<dim3(BATCH*NHEADS, SEQ/64), 256, 0, stream>>>(q, k, v, ctx);
  out_gemm<<<dim3(D_MODEL/64, NROWS/128), 256, 0, stream>>>(ctx, owb, out_b, out);
}

// Round 6
// 283.869 us; speedup vs baseline: 2.1888x; 1.2344x over previous
//
#include <hip/hip_runtime.h>

// MHR_76965813945133: x->QKV proj -> 3x causal MHA (Q<-ctx, K/V fixed) -> out proj.
// B=2, S=2048, D=1024, NH=16, HD=64. bf16 MFMA compute, fp32 accum.
// R6: attn3 back to 2-wave blocks (R3 topology, which beat R5's parity split) with:
//     (1) ping-pong K/V LDS buffers -> ONE barrier per kt tile (was 2);
//     (2) V stored pre-transposed (vT[bh][d][s]) by qkv_gemm's epilogue (free there:
//         C-frag values are s-consecutive -> packed 8B store), so attn3 V staging
//         is 4x b128 like K -- no perms, no b32 writes, no bank conflicts.

#define D_MODEL 1024
#define NHEADS  16
#define HD      64
#define SEQ     2048
#define BATCH   2
#define NROWS   (BATCH*SEQ)   // 4096
#define NQKV    (3*D_MODEL)   // 3072
#define SCL2F   0.1803368801111601f      // 0.125 * log2(e)
#define MASK2   (-14426.950408889634f)   // -10000 * log2(e)

typedef __bf16 bf16x8 __attribute__((ext_vector_type(8)));
typedef float  f32x4  __attribute__((ext_vector_type(4)));
typedef unsigned short us8 __attribute__((ext_vector_type(8)));
typedef unsigned short us4 __attribute__((ext_vector_type(4)));
typedef short  s16x4  __attribute__((ext_vector_type(4)));

__device__ __forceinline__ unsigned short f2bf(float f) {
  unsigned int u = __float_as_uint(f);
  u = (u + 0x7fffu + ((u >> 16) & 1u)) >> 16;   // RNE
  return (unsigned short)u;
}

union Pack8 { us8 v; unsigned short e[8]; };
union Pack4 { us4 v; unsigned short e[4]; };

__device__ __forceinline__ us8 cvt8(const float4 &a, const float4 &b) {
  Pack8 p;
  p.e[0]=f2bf(a.x); p.e[1]=f2bf(a.y); p.e[2]=f2bf(a.z); p.e[3]=f2bf(a.w);
  p.e[4]=f2bf(b.x); p.e[5]=f2bf(b.y); p.e[6]=f2bf(b.z); p.e[7]=f2bf(b.w);
  return p.v;
}

__device__ __forceinline__ void gl_lds16(const unsigned short* g, unsigned short* l) {
  __builtin_amdgcn_global_load_lds(
      (const __attribute__((address_space(1))) unsigned int*)g,
      (__attribute__((address_space(3))) unsigned int*)l, 16, 0, 0);
}

// ---------------- fp32 -> bf16 pre-convert (x, Wqkv_w, out_w) --------------------
#define CVT_N1 (NROWS*D_MODEL)    // 4194304
#define CVT_N2 (NQKV*D_MODEL)     // 3145728
#define CVT_N3 (D_MODEL*D_MODEL)  // 1048576

__global__ __launch_bounds__(256) void cvt_all(
    const float* __restrict__ x, const float* __restrict__ wq,
    const float* __restrict__ ow,
    unsigned short* __restrict__ xb, unsigned short* __restrict__ wqb,
    unsigned short* __restrict__ owb)
{
  size_t i = ((size_t)blockIdx.x * 256 + threadIdx.x) * 8;
  const float* src; unsigned short* dst; size_t off;
  if (i < CVT_N1)                { src = x;  dst = xb;  off = i; }
  else if (i < CVT_N1 + CVT_N2)  { src = wq; dst = wqb; off = i - CVT_N1; }
  else                           { src = ow; dst = owb; off = i - CVT_N1 - CVT_N2; }
  float4 a = *(const float4*)(src + off);
  float4 b = *(const float4*)(src + off + 4);
  *(us8*)(dst + off) = cvt8(a, b);
}

// ---------------- QKV GEMM: bf16, m97-style async staging ------------------------
// 128x128x32 tiles, 4 waves (2x2), 4x4 frags. As/Bs unpadded (DMA layout).
// Epilogue: q/k scattered [B,NH,S,HD] (q pre-scaled); v stored TRANSPOSED
// vT[b,h][d][s] via packed 8B stores (C-frag r-values are s-consecutive).
__global__ __launch_bounds__(256) void qkv_gemm(
    const unsigned short* __restrict__ xb, const unsigned short* __restrict__ wqb,
    const float* __restrict__ bias,
    unsigned short* __restrict__ q, unsigned short* __restrict__ k,
    unsigned short* __restrict__ vT)
{
  __shared__ __align__(16) unsigned short As[128*32];
  __shared__ __align__(16) unsigned short Bs[128*32];
  const int tid = threadIdx.x;
  const int m0 = blockIdx.y * 128, n0 = blockIdx.x * 128;
  const int wave = tid >> 6, lane = tid & 63;
  const int wm = (wave >> 1) * 64, wn = (wave & 1) * 64;
  const int lrow = lane & 15, quad = lane >> 4;

  const int c0 = wave * 2, c1 = wave * 2 + 1;
  const int drow0 = c0*16 + (lane >> 2), drow1 = c1*16 + (lane >> 2);
  const int dkoff = (lane & 3) * 8;
  const unsigned short* ga0 = xb  + (size_t)(m0 + drow0) * D_MODEL + dkoff;
  const unsigned short* ga1 = xb  + (size_t)(m0 + drow1) * D_MODEL + dkoff;
  const unsigned short* gb0 = wqb + (size_t)(n0 + drow0) * D_MODEL + dkoff;
  const unsigned short* gb1 = wqb + (size_t)(n0 + drow1) * D_MODEL + dkoff;
  unsigned short* la0 = &As[c0*512];
  unsigned short* la1 = &As[c1*512];
  unsigned short* lb0 = &Bs[c0*512];
  unsigned short* lb1 = &Bs[c1*512];

  f32x4 acc[4][4];
  #pragma unroll
  for (int i = 0; i < 4; i++)
    #pragma unroll
    for (int j = 0; j < 4; j++) acc[i][j] = (f32x4){0.f,0.f,0.f,0.f};

  for (int k0 = 0; k0 < D_MODEL; k0 += 32) {
    __syncthreads();
    gl_lds16(ga0 + k0, la0);
    gl_lds16(ga1 + k0, la1);
    gl_lds16(gb0 + k0, lb0);
    gl_lds16(gb1 + k0, lb1);
    __syncthreads();
    bf16x8 af[4], bfr[4];
    #pragma unroll
    for (int mf = 0; mf < 4; mf++)
      af[mf] = *(const bf16x8*)&As[(wm + mf*16 + lrow)*32 + quad*8];
    #pragma unroll
    for (int nb = 0; nb < 4; nb++)
      bfr[nb] = *(const bf16x8*)&Bs[(wn + nb*16 + lrow)*32 + quad*8];
    #pragma unroll
    for (int mf = 0; mf < 4; mf++)
      #pragma unroll
      for (int nb = 0; nb < 4; nb++)
        acc[mf][nb] = __builtin_amdgcn_mfma_f32_16x16x32_bf16(af[mf], bfr[nb], acc[mf][nb], 0, 0, 0);
  }

  #pragma unroll
  for (int mf = 0; mf < 4; mf++) {
    #pragma unroll
    for (int nb = 0; nb < 4; nb++) {
      int n = n0 + wn + nb*16 + lrow;
      int which = n >> 10;
      int h  = (n >> 6) & 15;
      int hd = n & 63;
      int mb = m0 + wm + mf*16 + quad*4;
      int b  = mb >> 11;
      int s  = mb & 2047;
      float bi = bias[n];
      if (which == 2) {
        Pack4 p4;
        #pragma unroll
        for (int r = 0; r < 4; r++) p4.e[r] = f2bf(acc[mf][nb][r] + bi);
        *(us4*)&vT[((size_t)((b*NHEADS + h)*HD + hd))*SEQ + s] = p4.v;
      } else {
        unsigned short* dst = (which == 0) ? q : k;
        float scl = (which == 0) ? SCL2F : 1.0f;
        #pragma unroll
        for (int r = 0; r < 4; r++)
          dst[(size_t)((b*NHEADS + h)*SEQ + s + r)*HD + hd] = f2bf((acc[mf][nb][r] + bi) * scl);
      }
    }
  }
}

// ---------------- fused 3-rep causal flash attention ------------------------------
// 128-thr blocks (2 waves), 64-q tiles, 32 q/wave, grid (bh=32, y=32),
// qt=(x+y)&31 balance swizzle. Ping-pong K/V buffers: ONE barrier per kt tile.
#define LDQ 72   // 144B rows, 16B-aligned, 2-way banks (free)

__global__ __launch_bounds__(128) void attn3(
    const unsigned short* __restrict__ qg,
    const unsigned short* __restrict__ kg,
    const unsigned short* __restrict__ vTg,
    unsigned short* __restrict__ ctx)
{
  __shared__ __align__(16) unsigned short Ks[2][64*LDQ];
  __shared__ __align__(16) unsigned short Vs[2][64*LDQ];   // Vs[d][s] (pre-transposed)

  const int tid  = threadIdx.x;
  const int w    = tid >> 6, lane = tid & 63;
  const int lrow = lane & 15, quad = lane >> 4;
  const int bh = blockIdx.x;
  const int qt = (blockIdx.x + blockIdx.y) & 31;   // balance swizzle
  const unsigned short* qbase = qg  + (size_t)bh * SEQ * HD;
  const unsigned short* kbase = kg  + (size_t)bh * SEQ * HD;
  const unsigned short* vbase = vTg + (size_t)bh * HD * SEQ;
  unsigned short* cbase = ctx + (size_t)bh * SEQ * HD;

  const int srow = tid >> 1, sc0 = (tid & 1) * 32;   // staging map (K rows / vT rows)

  // stage Q tile (rows qt*64..+63, pre-scaled) into Ks[0]
  {
    const unsigned short* src = qbase + (size_t)(qt*64 + srow)*HD + sc0;
    *(uint4*)&Ks[0][srow*LDQ + sc0]      = *(const uint4*)src;
    *(uint4*)&Ks[0][srow*LDQ + sc0 + 8]  = *(const uint4*)(src + 8);
    *(uint4*)&Ks[0][srow*LDQ + sc0 + 16] = *(const uint4*)(src + 16);
    *(uint4*)&Ks[0][srow*LDQ + sc0 + 24] = *(const uint4*)(src + 24);
  }
  __syncthreads();

  // Q as K=32 B-operand frags: B[k=d=quad*8+j][n=q=lane&15]
  bf16x8 qb[2][2];
  #pragma unroll
  for (int qgi = 0; qgi < 2; qgi++) {
    qb[qgi][0] = *(const bf16x8*)&Ks[0][(w*32 + qgi*16 + lrow)*LDQ + quad*8];
    qb[qgi][1] = *(const bf16x8*)&Ks[0][(w*32 + qgi*16 + lrow)*LDQ + 32 + quad*8];
  }
  __syncthreads();   // qb reads done before first K store overwrites Ks[0]

  for (int rep = 0; rep < 3; ++rep) {
    f32x4 od[2][4];
    #pragma unroll
    for (int qgi = 0; qgi < 2; qgi++)
      #pragma unroll
      for (int df = 0; df < 4; df++) od[qgi][df] = (f32x4){0.f,0.f,0.f,0.f};
    float ls[2] = {0.f, 0.f};

    // prefetch kt=0
    uint4 kr0, kr1, kr2, kr3, vr0, vr1, vr2, vr3;
    {
      const unsigned short* ks = kbase + (size_t)srow*HD + sc0;
      kr0 = *(const uint4*)ks;        kr1 = *(const uint4*)(ks + 8);
      kr2 = *(const uint4*)(ks + 16); kr3 = *(const uint4*)(ks + 24);
      const unsigned short* vs = vbase + (size_t)srow*SEQ + sc0;
      vr0 = *(const uint4*)vs;        vr1 = *(const uint4*)(vs + 8);
      vr2 = *(const uint4*)(vs + 16); vr3 = *(const uint4*)(vs + 24);
    }

    for (int kt = 0; kt <= qt; ++kt) {
      const int b = kt & 1;
      // store prefetched tile into ping-pong buffer b
      *(uint4*)&Ks[b][srow*LDQ + sc0]      = kr0;
      *(uint4*)&Ks[b][srow*LDQ + sc0 + 8]  = kr1;
      *(uint4*)&Ks[b][srow*LDQ + sc0 + 16] = kr2;
      *(uint4*)&Ks[b][srow*LDQ + sc0 + 24] = kr3;
      *(uint4*)&Vs[b][srow*LDQ + sc0]      = vr0;
      *(uint4*)&Vs[b][srow*LDQ + sc0 + 8]  = vr1;
      *(uint4*)&Vs[b][srow*LDQ + sc0 + 16] = vr2;
      *(uint4*)&Vs[b][srow*LDQ + sc0 + 24] = vr3;
      // prefetch kt+1 (in flight across barrier + compute)
      if (kt < qt) {
        const unsigned short* ks = kbase + (size_t)((kt+1)*64 + srow)*HD + sc0;
        kr0 = *(const uint4*)ks;        kr1 = *(const uint4*)(ks + 8);
        kr2 = *(const uint4*)(ks + 16); kr3 = *(const uint4*)(ks + 24);
        const unsigned short* vs = vbase + (size_t)srow*SEQ + (kt+1)*64 + sc0;
        vr0 = *(const uint4*)vs;        vr1 = *(const uint4*)(vs + 8);
        vr2 = *(const uint4*)(vs + 16); vr3 = *(const uint4*)(vs + 24);
      }
      __syncthreads();   // the ONLY barrier per tile

      // scores: S^T = K * Q^T (K=32 MFMA), A-frags shared across q-groups
      f32x4 sc[2][4];
      #pragma unroll
      for (int sf = 0; sf < 4; sf++) {
        bf16x8 a0 = *(const bf16x8*)&Ks[b][(sf*16 + lrow)*LDQ + quad*8];
        bf16x8 a1 = *(const bf16x8*)&Ks[b][(sf*16 + lrow)*LDQ + 32 + quad*8];
        f32x4 z0 = (f32x4){0.f,0.f,0.f,0.f}, z1 = z0;
        z0 = __builtin_amdgcn_mfma_f32_16x16x32_bf16(a0, qb[0][0], z0, 0, 0, 0);
        z1 = __builtin_amdgcn_mfma_f32_16x16x32_bf16(a0, qb[1][0], z1, 0, 0, 0);
        z0 = __builtin_amdgcn_mfma_f32_16x16x32_bf16(a1, qb[0][1], z0, 0, 0, 0);
        z1 = __builtin_amdgcn_mfma_f32_16x16x32_bf16(a1, qb[1][1], z1, 0, 0, 0);
        sc[0][sf] = z0; sc[1][sf] = z1;
      }
      if (kt == qt) {   // causal mask, exp2 domain
        #pragma unroll
        for (int qgi = 0; qgi < 2; qgi++) {
          int ql = w*32 + qgi*16 + lrow;
          #pragma unroll
          for (int sf = 0; sf < 4; sf++)
            #pragma unroll
            for (int r = 0; r < 4; r++)
              if (sf*16 + quad*4 + r > ql) sc[qgi][sf][r] += MASK2;
        }
      }
      // p = exp2(s) (bounded scores, no-max softmax); P lands in K=16 B-layout
      s16x4 pf[2][4];
      #pragma unroll
      for (int qgi = 0; qgi < 2; qgi++) {
        float lp = 0.f;
        #pragma unroll
        for (int sf = 0; sf < 4; sf++) {
          Pack4 pk;
          #pragma unroll
          for (int r = 0; r < 4; r++) {
            float pe = __builtin_amdgcn_exp2f(sc[qgi][sf][r]);
            lp += pe;
            pk.e[r] = __builtin_bit_cast(unsigned short, (__bf16)pe);
          }
          pf[qgi][sf] = __builtin_bit_cast(s16x4, pk.v);
        }
        ls[qgi] += lp;
      }
      // PV: O^T += V^T * P^T (K=16), A-frags from Vs shared across q-groups
      #pragma unroll
      for (int df = 0; df < 4; df++) {
        s16x4 v0 = *(const s16x4*)&Vs[b][(df*16 + lrow)*LDQ +  0 + quad*4];
        s16x4 v1 = *(const s16x4*)&Vs[b][(df*16 + lrow)*LDQ + 16 + quad*4];
        s16x4 v2 = *(const s16x4*)&Vs[b][(df*16 + lrow)*LDQ + 32 + quad*4];
        s16x4 v3 = *(const s16x4*)&Vs[b][(df*16 + lrow)*LDQ + 48 + quad*4];
        od[0][df] = __builtin_amdgcn_mfma_f32_16x16x16bf16_1k(v0, pf[0][0], od[0][df], 0, 0, 0);
        od[1][df] = __builtin_amdgcn_mfma_f32_16x16x16bf16_1k(v0, pf[1][0], od[1][df], 0, 0, 0);
        od[0][df] = __builtin_amdgcn_mfma_f32_16x16x16bf16_1k(v1, pf[0][1], od[0][df], 0, 0, 0);
        od[1][df] = __builtin_amdgcn_mfma_f32_16x16x16bf16_1k(v1, pf[1][1], od[1][df], 0, 0, 0);
        od[0][df] = __builtin_amdgcn_mfma_f32_16x16x16bf16_1k(v2, pf[0][2], od[0][df], 0, 0, 0);
        od[1][df] = __builtin_amdgcn_mfma_f32_16x16x16bf16_1k(v2, pf[1][2], od[1][df], 0, 0, 0);
        od[0][df] = __builtin_amdgcn_mfma_f32_16x16x16bf16_1k(v3, pf[0][3], od[0][df], 0, 0, 0);
        od[1][df] = __builtin_amdgcn_mfma_f32_16x16x16bf16_1k(v3, pf[1][3], od[1][df], 0, 0, 0);
      }
    } // kt

    // reduce l across quads (q id depends only on lane&15)
    #pragma unroll
    for (int qgi = 0; qgi < 2; qgi++) {
      ls[qgi] += __shfl_xor(ls[qgi], 16);
      ls[qgi] += __shfl_xor(ls[qgi], 32);
    }

    __syncthreads();   // all tile consumers done; safe to overwrite Ks[0]
    #pragma unroll
    for (int qgi = 0; qgi < 2; qgi++) {
      float f = ((rep < 2) ? SCL2F : 1.0f) / ls[qgi];
      #pragma unroll
      for (int df = 0; df < 4; df++) {
        Pack4 pk;
        #pragma unroll
        for (int r = 0; r < 4; r++)
          pk.e[r] = __builtin_bit_cast(unsigned short, (__bf16)(od[qgi][df][r] * f));
        *(us4*)&Ks[0][(w*32 + qgi*16 + lrow)*LDQ + df*16 + quad*4] = pk.v;
      }
    }
    __syncthreads();
    if (rep < 2) {   // reload chained Q frags
      #pragma unroll
      for (int qgi = 0; qgi < 2; qgi++) {
        qb[qgi][0] = *(const bf16x8*)&Ks[0][(w*32 + qgi*16 + lrow)*LDQ + quad*8];
        qb[qgi][1] = *(const bf16x8*)&Ks[0][(w*32 + qgi*16 + lrow)*LDQ + 32 + quad*8];
      }
      __syncthreads();   // reloads done before next rep's kt=0 store to Ks[0]
    }
  } // rep

  {   // coalesced ctx store from Ks[0]
    unsigned short* dst = cbase + (size_t)(qt*64 + srow)*HD + sc0;
    *(uint4*)dst        = *(const uint4*)&Ks[0][srow*LDQ + sc0];
    *(uint4*)(dst + 8)  = *(const uint4*)&Ks[0][srow*LDQ + sc0 + 8];
    *(uint4*)(dst + 16) = *(const uint4*)&Ks[0][srow*LDQ + sc0 + 16];
    *(uint4*)(dst + 24) = *(const uint4*)&Ks[0][srow*LDQ + sc0 + 24];
  }
}

// ---------------- out projection: 128x64x32 tiles, async staging, fp32 out -------
__global__ __launch_bounds__(256) void out_gemm(
    const unsigned short* __restrict__ ctx, const unsigned short* __restrict__ owb,
    const float* __restrict__ bias, float* __restrict__ out)
{
  __shared__ __align__(16) unsigned short As[128*32];
  __shared__ __align__(16) unsigned short Bs[64*32];
  const int tid = threadIdx.x;
  const int m0 = blockIdx.y * 128, n0 = blockIdx.x * 64;
  const int wave = tid >> 6, lane = tid & 63;
  const int wm = (wave >> 1) * 64, wn = (wave & 1) * 32;
  const int lrow = lane & 15, quad = lane >> 4;

  const int dl = lane >> 2, dkoff = (lane & 3) * 8;
  const int ar0 = wave*16 + dl, ar1 = (wave+4)*16 + dl;
  const int am0 = m0 + ar0, am1 = m0 + ar1;
  const size_t abase0 = ((size_t)((am0 >> 11)*NHEADS)*SEQ + (am0 & 2047))*HD;
  const size_t abase1 = ((size_t)((am1 >> 11)*NHEADS)*SEQ + (am1 & 2047))*HD;
  const unsigned short* gb = owb + (size_t)(n0 + wave*16 + dl) * D_MODEL + dkoff;
  unsigned short* la0 = &As[wave*512];
  unsigned short* la1 = &As[(wave+4)*512];
  unsigned short* lb  = &Bs[wave*512];

  f32x4 acc[4][2];
  #pragma unroll
  for (int i = 0; i < 4; i++)
    #pragma unroll
    for (int j = 0; j < 2; j++) acc[i][j] = (f32x4){0.f,0.f,0.f,0.f};

  for (int k0 = 0; k0 < D_MODEL; k0 += 32) {
    int kk = k0 + dkoff;
    int h = kk >> 6, hd = kk & 63;
    size_t hoff = (size_t)h * SEQ * HD + hd;
    __syncthreads();
    gl_lds16(ctx + abase0 + hoff, la0);
    gl_lds16(ctx + abase1 + hoff, la1);
    gl_lds16(gb + k0, lb);
    __syncthreads();
    bf16x8 af[4], bfr[2];
    #pragma unroll
    for (int mf = 0; mf < 4; mf++)
      af[mf] = *(const bf16x8*)&As[(wm + mf*16 + lrow)*32 + quad*8];
    #pragma unroll
    for (int nb = 0; nb < 2; nb++)
      bfr[nb] = *(const bf16x8*)&Bs[(wn + nb*16 + lrow)*32 + quad*8];
    #pragma unroll
    for (int mf = 0; mf < 4; mf++)
      #pragma unroll
      for (int nb = 0; nb < 2; nb++)
        acc[mf][nb] = __builtin_amdgcn_mfma_f32_16x16x32_bf16(af[mf], bfr[nb], acc[mf][nb], 0, 0, 0);
  }

  #pragma unroll
  for (int mf = 0; mf < 4; mf++) {
    #pragma unroll
    for (int nb = 0; nb < 2; nb++) {
      #pragma unroll
      for (int r = 0; r < 4; r++) {
        int mm = m0 + wm + mf*16 + quad*4 + r;
        int n  = n0 + wn + nb*16 + lrow;
        out[(size_t)mm * D_MODEL + n] = acc[mf][nb][r] + bias[n];
      }
    }
  }
}

extern "C" void kernel_launch(void* const* d_in, const int* in_sizes, int n_in,
                              void* d_out, int out_size, void* d_ws, size_t ws_size,
                              hipStream_t stream) {
  (void)in_sizes; (void)n_in; (void)out_size; (void)ws_size;
  const float* x      = (const float*)d_in[0];
  const float* Wqkv_w = (const float*)d_in[1];
  const float* Wqkv_b = (const float*)d_in[2];
  const float* out_w  = (const float*)d_in[3];
  const float* out_b  = (const float*)d_in[4];
  float* out = (float*)d_out;

  unsigned short* ws = (unsigned short*)d_ws;
  unsigned short* xb  = ws;                              // 4.19M elems; reused as ctx
  unsigned short* wqb = ws + CVT_N1;                     // 3.15M
  unsigned short* owb = ws + CVT_N1 + CVT_N2;            // 1.05M
  unsigned short* q   = ws + CVT_N1 + CVT_N2 + CVT_N3;   // 4.19M each
  unsigned short* k   = q + (size_t)NROWS*D_MODEL;
  unsigned short* vT  = k + (size_t)NROWS*D_MODEL;       // [bh][d][s] transposed
  unsigned short* ctx = xb;                              // alias: xb dead after qkv

  cvt_all<<<(CVT_N1+CVT_N2+CVT_N3)/(256*8), 256, 0, stream>>>(x, Wqkv_w, out_w, xb, wqb, owb);
  qkv_gemm<<<dim3(NQKV/128, NROWS/128), 256, 0, stream>>>(xb, wqb, Wqkv_b, q, k, vT);
  attn3<<<dim3(BATCH*NHEADS, SEQ/64), 128, 0, stream>>>(q, k, vT, ctx);
  out_gemm<<<dim3(D_MODEL/64, NROWS/128), 256, 0, stream>>>(ctx, owb, out_b, out);
}

// Round 8
// 256.178 us; speedup vs baseline: 2.4253x; 1.1081x over previous
//
#include <hip/hip_runtime.h>

// MHR_76965813945133: x->QKV proj -> 3x causal MHA (Q<-ctx, K/V fixed) -> out proj.
// B=2, S=2048, D=1024, NH=16, HD=64. bf16 MFMA compute, fp32 accum.
// R8: R7 with the swizzle bug fixed: base must be &7 (not &15) for the mirror
//     qt map to be a permutation. R7 dropped qt tiles (poisoned ctx) and raced
//     on duplicated ones. All else identical to R7.

#define D_MODEL 1024
#define NHEADS  16
#define HD      64
#define SEQ     2048
#define BATCH   2
#define NROWS   (BATCH*SEQ)   // 4096
#define NQKV    (3*D_MODEL)   // 3072
#define SCL2F   0.1803368801111601f      // 0.125 * log2(e)
#define MASK2   (-14426.950408889634f)   // -10000 * log2(e)

typedef __bf16 bf16x8 __attribute__((ext_vector_type(8)));
typedef float  f32x4  __attribute__((ext_vector_type(4)));
typedef unsigned short us8 __attribute__((ext_vector_type(8)));
typedef unsigned short us4 __attribute__((ext_vector_type(4)));
typedef short  s16x4  __attribute__((ext_vector_type(4)));

__device__ __forceinline__ unsigned short f2bf(float f) {
  unsigned int u = __float_as_uint(f);
  u = (u + 0x7fffu + ((u >> 16) & 1u)) >> 16;   // RNE
  return (unsigned short)u;
}

union Pack8 { us8 v; unsigned short e[8]; };
union Pack4 { us4 v; unsigned short e[4]; };

__device__ __forceinline__ us8 cvt8(const float4 &a, const float4 &b) {
  Pack8 p;
  p.e[0]=f2bf(a.x); p.e[1]=f2bf(a.y); p.e[2]=f2bf(a.z); p.e[3]=f2bf(a.w);
  p.e[4]=f2bf(b.x); p.e[5]=f2bf(b.y); p.e[6]=f2bf(b.z); p.e[7]=f2bf(b.w);
  return p.v;
}

__device__ __forceinline__ void gl_lds16(const unsigned short* g, unsigned short* l) {
  __builtin_amdgcn_global_load_lds(
      (const __attribute__((address_space(1))) unsigned int*)g,
      (__attribute__((address_space(3))) unsigned int*)l, 16, 0, 0);
}

// ---------------- fp32 -> bf16 pre-convert (x, Wqkv_w, out_w) --------------------
#define CVT_N1 (NROWS*D_MODEL)    // 4194304
#define CVT_N2 (NQKV*D_MODEL)     // 3145728
#define CVT_N3 (D_MODEL*D_MODEL)  // 1048576

__global__ __launch_bounds__(256) void cvt_all(
    const float* __restrict__ x, const float* __restrict__ wq,
    const float* __restrict__ ow,
    unsigned short* __restrict__ xb, unsigned short* __restrict__ wqb,
    unsigned short* __restrict__ owb)
{
  size_t i = ((size_t)blockIdx.x * 256 + threadIdx.x) * 8;
  const float* src; unsigned short* dst; size_t off;
  if (i < CVT_N1)                { src = x;  dst = xb;  off = i; }
  else if (i < CVT_N1 + CVT_N2)  { src = wq; dst = wqb; off = i - CVT_N1; }
  else                           { src = ow; dst = owb; off = i - CVT_N1 - CVT_N2; }
  float4 a = *(const float4*)(src + off);
  float4 b = *(const float4*)(src + off + 4);
  *(us8*)(dst + off) = cvt8(a, b);
}

// ---------------- QKV GEMM: bf16, m97-style async staging ------------------------
__global__ __launch_bounds__(256) void qkv_gemm(
    const unsigned short* __restrict__ xb, const unsigned short* __restrict__ wqb,
    const float* __restrict__ bias,
    unsigned short* __restrict__ q, unsigned short* __restrict__ k,
    unsigned short* __restrict__ vT)
{
  __shared__ __align__(16) unsigned short As[128*32];
  __shared__ __align__(16) unsigned short Bs[128*32];
  const int tid = threadIdx.x;
  const int m0 = blockIdx.y * 128, n0 = blockIdx.x * 128;
  const int wave = tid >> 6, lane = tid & 63;
  const int wm = (wave >> 1) * 64, wn = (wave & 1) * 64;
  const int lrow = lane & 15, quad = lane >> 4;

  const int c0 = wave * 2, c1 = wave * 2 + 1;
  const int drow0 = c0*16 + (lane >> 2), drow1 = c1*16 + (lane >> 2);
  const int dkoff = (lane & 3) * 8;
  const unsigned short* ga0 = xb  + (size_t)(m0 + drow0) * D_MODEL + dkoff;
  const unsigned short* ga1 = xb  + (size_t)(m0 + drow1) * D_MODEL + dkoff;
  const unsigned short* gb0 = wqb + (size_t)(n0 + drow0) * D_MODEL + dkoff;
  const unsigned short* gb1 = wqb + (size_t)(n0 + drow1) * D_MODEL + dkoff;
  unsigned short* la0 = &As[c0*512];
  unsigned short* la1 = &As[c1*512];
  unsigned short* lb0 = &Bs[c0*512];
  unsigned short* lb1 = &Bs[c1*512];

  f32x4 acc[4][4];
  #pragma unroll
  for (int i = 0; i < 4; i++)
    #pragma unroll
    for (int j = 0; j < 4; j++) acc[i][j] = (f32x4){0.f,0.f,0.f,0.f};

  for (int k0 = 0; k0 < D_MODEL; k0 += 32) {
    __syncthreads();
    gl_lds16(ga0 + k0, la0);
    gl_lds16(ga1 + k0, la1);
    gl_lds16(gb0 + k0, lb0);
    gl_lds16(gb1 + k0, lb1);
    __syncthreads();
    bf16x8 af[4], bfr[4];
    #pragma unroll
    for (int mf = 0; mf < 4; mf++)
      af[mf] = *(const bf16x8*)&As[(wm + mf*16 + lrow)*32 + quad*8];
    #pragma unroll
    for (int nb = 0; nb < 4; nb++)
      bfr[nb] = *(const bf16x8*)&Bs[(wn + nb*16 + lrow)*32 + quad*8];
    #pragma unroll
    for (int mf = 0; mf < 4; mf++)
      #pragma unroll
      for (int nb = 0; nb < 4; nb++)
        acc[mf][nb] = __builtin_amdgcn_mfma_f32_16x16x32_bf16(af[mf], bfr[nb], acc[mf][nb], 0, 0, 0);
  }

  #pragma unroll
  for (int mf = 0; mf < 4; mf++) {
    #pragma unroll
    for (int nb = 0; nb < 4; nb++) {
      int n = n0 + wn + nb*16 + lrow;
      int which = n >> 10;
      int h  = (n >> 6) & 15;
      int hd = n & 63;
      int mb = m0 + wm + mf*16 + quad*4;
      int b  = mb >> 11;
      int s  = mb & 2047;
      float bi = bias[n];
      if (which == 2) {
        Pack4 p4;
        #pragma unroll
        for (int r = 0; r < 4; r++) p4.e[r] = f2bf(acc[mf][nb][r] + bi);
        *(us4*)&vT[((size_t)((b*NHEADS + h)*HD + hd))*SEQ + s] = p4.v;
      } else {
        unsigned short* dst = (which == 0) ? q : k;
        float scl = (which == 0) ? SCL2F : 1.0f;
        #pragma unroll
        for (int r = 0; r < 4; r++)
          dst[(size_t)((b*NHEADS + h)*SEQ + s + r)*HD + hd] = f2bf((acc[mf][nb][r] + bi) * scl);
      }
    }
  }
}

// ---------------- fused 3-rep causal flash attention ------------------------------
// 256-thr blocks (4 waves), 128-q tiles (32 q/wave), grid (bh=32, y=16).
// Mirror qt swizzle (base in 0..7!): co-resident pairs (yy, yy+8) sum to 15.
#define LDQ 72   // 144B rows, 16B-aligned, 2-way banks (free)

__global__ __launch_bounds__(256) void attn3(
    const unsigned short* __restrict__ qg,
    const unsigned short* __restrict__ kg,
    const unsigned short* __restrict__ vTg,
    unsigned short* __restrict__ ctx)
{
  __shared__ __align__(16) unsigned short Ks[2][64*LDQ];
  __shared__ __align__(16) unsigned short Vs[2][64*LDQ];   // Vs[d][s]; also Q-chain buf
  unsigned short* QC = &Vs[0][0];                          // 128 rows x LDQ (spans Vs)

  const int tid  = threadIdx.x;
  const int w    = tid >> 6, lane = tid & 63;
  const int lrow = lane & 15, quad = lane >> 4;
  const int bh = blockIdx.x;
  const int yy = blockIdx.y;
  const int base = (blockIdx.x + yy) & 7;          // 0..7 (required for mirror!)
  const int qt = (yy < 8) ? base : (15 - base);    // permutation over 0..15
  const unsigned short* qbase = qg  + (size_t)bh * SEQ * HD;
  const unsigned short* kbase = kg  + (size_t)bh * SEQ * HD;
  const unsigned short* vbase = vTg + (size_t)bh * HD * SEQ;
  unsigned short* cbase = ctx + (size_t)bh * SEQ * HD;

  const int srow = tid >> 2;                       // 64x64 staging map
  const int sco  = (tid & 3) * 16;
  const int qrow = tid >> 1, qc0 = (tid & 1) * 32; // 128-row Q map

  // stage Q tile (rows qt*128..+127, pre-scaled) into QC
  {
    const unsigned short* src = qbase + (size_t)(qt*128 + qrow)*HD + qc0;
    *(uint4*)&QC[qrow*LDQ + qc0]      = *(const uint4*)src;
    *(uint4*)&QC[qrow*LDQ + qc0 + 8]  = *(const uint4*)(src + 8);
    *(uint4*)&QC[qrow*LDQ + qc0 + 16] = *(const uint4*)(src + 16);
    *(uint4*)&QC[qrow*LDQ + qc0 + 24] = *(const uint4*)(src + 24);
  }
  __syncthreads();

  // Q as K=32 B-operand frags: B[k=d=quad*8+j][n=q=lane&15]
  bf16x8 qb[2][2];
  #pragma unroll
  for (int qgi = 0; qgi < 2; qgi++) {
    qb[qgi][0] = *(const bf16x8*)&QC[(w*32 + qgi*16 + lrow)*LDQ + quad*8];
    qb[qgi][1] = *(const bf16x8*)&QC[(w*32 + qgi*16 + lrow)*LDQ + 32 + quad*8];
  }
  __syncthreads();   // qb reads done before kt=0 store overwrites Vs

  const int kmax = 2*qt + 1;          // last kt tile index
  const int qwbase = qt*128 + w*32;   // this wave's lowest q row

  for (int rep = 0; rep < 3; ++rep) {
    f32x4 od[2][4];
    #pragma unroll
    for (int qgi = 0; qgi < 2; qgi++)
      #pragma unroll
      for (int df = 0; df < 4; df++) od[qgi][df] = (f32x4){0.f,0.f,0.f,0.f};
    float ls[2] = {0.f, 0.f};

    // prefetch kt=0 (2 uint4 K + 2 uint4 V per thread)
    uint4 kr0, kr1, vr0, vr1;
    {
      const unsigned short* ks = kbase + (size_t)srow*HD + sco;
      kr0 = *(const uint4*)ks;  kr1 = *(const uint4*)(ks + 8);
      const unsigned short* vs = vbase + (size_t)srow*SEQ + sco;
      vr0 = *(const uint4*)vs;  vr1 = *(const uint4*)(vs + 8);
    }

    for (int kt = 0; kt <= kmax; ++kt) {
      const int b = kt & 1;
      *(uint4*)&Ks[b][srow*LDQ + sco]     = kr0;
      *(uint4*)&Ks[b][srow*LDQ + sco + 8] = kr1;
      *(uint4*)&Vs[b][srow*LDQ + sco]     = vr0;
      *(uint4*)&Vs[b][srow*LDQ + sco + 8] = vr1;
      if (kt < kmax) {
        const unsigned short* ks = kbase + (size_t)((kt+1)*64 + srow)*HD + sco;
        kr0 = *(const uint4*)ks;  kr1 = *(const uint4*)(ks + 8);
        const unsigned short* vs = vbase + (size_t)srow*SEQ + (kt+1)*64 + sco;
        vr0 = *(const uint4*)vs;  vr1 = *(const uint4*)(vs + 8);
      }
      __syncthreads();   // the only barrier per tile

      const int sbase = kt*64;
      const bool skip = sbase > (qwbase + 31);        // wave fully masked
      if (!skip) {
        // scores: S^T = K * Q^T (K=32), A-frags shared across both q-groups
        f32x4 sc[2][4];
        #pragma unroll
        for (int sf = 0; sf < 4; sf++) {
          bf16x8 a0 = *(const bf16x8*)&Ks[b][(sf*16 + lrow)*LDQ + quad*8];
          bf16x8 a1 = *(const bf16x8*)&Ks[b][(sf*16 + lrow)*LDQ + 32 + quad*8];
          f32x4 z0 = (f32x4){0.f,0.f,0.f,0.f}, z1 = z0;
          z0 = __builtin_amdgcn_mfma_f32_16x16x32_bf16(a0, qb[0][0], z0, 0, 0, 0);
          z1 = __builtin_amdgcn_mfma_f32_16x16x32_bf16(a0, qb[1][0], z1, 0, 0, 0);
          z0 = __builtin_amdgcn_mfma_f32_16x16x32_bf16(a1, qb[0][1], z0, 0, 0, 0);
          z1 = __builtin_amdgcn_mfma_f32_16x16x32_bf16(a1, qb[1][1], z1, 0, 0, 0);
          sc[0][sf] = z0; sc[1][sf] = z1;
        }
        if (sbase + 63 > qwbase) {   // element mask needed (last two kt only)
          #pragma unroll
          for (int qgi = 0; qgi < 2; qgi++) {
            int ql = qwbase + qgi*16 + lrow;
            #pragma unroll
            for (int sf = 0; sf < 4; sf++)
              #pragma unroll
              for (int r = 0; r < 4; r++)
                if (sbase + sf*16 + quad*4 + r > ql) sc[qgi][sf][r] += MASK2;
          }
        }
        // p = exp2(s); P lands directly in K=16 B-layout
        s16x4 pf[2][4];
        #pragma unroll
        for (int qgi = 0; qgi < 2; qgi++) {
          float lp = 0.f;
          #pragma unroll
          for (int sf = 0; sf < 4; sf++) {
            Pack4 pk;
            #pragma unroll
            for (int r = 0; r < 4; r++) {
              float pe = __builtin_amdgcn_exp2f(sc[qgi][sf][r]);
              lp += pe;
              pk.e[r] = __builtin_bit_cast(unsigned short, (__bf16)pe);
            }
            pf[qgi][sf] = __builtin_bit_cast(s16x4, pk.v);
          }
          ls[qgi] += lp;
        }
        // PV: O^T += V^T * P^T (K=16)
        #pragma unroll
        for (int df = 0; df < 4; df++) {
          s16x4 v0 = *(const s16x4*)&Vs[b][(df*16 + lrow)*LDQ +  0 + quad*4];
          s16x4 v1 = *(const s16x4*)&Vs[b][(df*16 + lrow)*LDQ + 16 + quad*4];
          s16x4 v2 = *(const s16x4*)&Vs[b][(df*16 + lrow)*LDQ + 32 + quad*4];
          s16x4 v3 = *(const s16x4*)&Vs[b][(df*16 + lrow)*LDQ + 48 + quad*4];
          od[0][df] = __builtin_amdgcn_mfma_f32_16x16x16bf16_1k(v0, pf[0][0], od[0][df], 0, 0, 0);
          od[1][df] = __builtin_amdgcn_mfma_f32_16x16x16bf16_1k(v0, pf[1][0], od[1][df], 0, 0, 0);
          od[0][df] = __builtin_amdgcn_mfma_f32_16x16x16bf16_1k(v1, pf[0][1], od[0][df], 0, 0, 0);
          od[1][df] = __builtin_amdgcn_mfma_f32_16x16x16bf16_1k(v1, pf[1][1], od[1][df], 0, 0, 0);
          od[0][df] = __builtin_amdgcn_mfma_f32_16x16x16bf16_1k(v2, pf[0][2], od[0][df], 0, 0, 0);
          od[1][df] = __builtin_amdgcn_mfma_f32_16x16x16bf16_1k(v2, pf[1][2], od[1][df], 0, 0, 0);
          od[0][df] = __builtin_amdgcn_mfma_f32_16x16x16bf16_1k(v3, pf[0][3], od[0][df], 0, 0, 0);
          od[1][df] = __builtin_amdgcn_mfma_f32_16x16x16bf16_1k(v3, pf[1][3], od[1][df], 0, 0, 0);
        }
      }
    } // kt

    // reduce l across quads (q id depends only on lane&15)
    #pragma unroll
    for (int qgi = 0; qgi < 2; qgi++) {
      ls[qgi] += __shfl_xor(ls[qgi], 16);
      ls[qgi] += __shfl_xor(ls[qgi], 32);
    }

    __syncthreads();   // all Ks/Vs readers done; QC (=Vs) is free
    #pragma unroll
    for (int qgi = 0; qgi < 2; qgi++) {
      float f = ((rep < 2) ? SCL2F : 1.0f) / ls[qgi];
      #pragma unroll
      for (int df = 0; df < 4; df++) {
        Pack4 pk;
        #pragma unroll
        for (int r = 0; r < 4; r++)
          pk.e[r] = __builtin_bit_cast(unsigned short, (__bf16)(od[qgi][df][r] * f));
        *(us4*)&QC[(w*32 + qgi*16 + lrow)*LDQ + df*16 + quad*4] = pk.v;
      }
    }
    __syncthreads();
    if (rep < 2) {   // reload chained Q frags
      #pragma unroll
      for (int qgi = 0; qgi < 2; qgi++) {
        qb[qgi][0] = *(const bf16x8*)&QC[(w*32 + qgi*16 + lrow)*LDQ + quad*8];
        qb[qgi][1] = *(const bf16x8*)&QC[(w*32 + qgi*16 + lrow)*LDQ + 32 + quad*8];
      }
      __syncthreads();   // reloads done before next rep's kt=0 store to Vs
    }
  } // rep

  {   // coalesced ctx store from QC
    unsigned short* dst = cbase + (size_t)(qt*128 + qrow)*HD + qc0;
    *(uint4*)dst        = *(const uint4*)&QC[qrow*LDQ + qc0];
    *(uint4*)(dst + 8)  = *(const uint4*)&QC[qrow*LDQ + qc0 + 8];
    *(uint4*)(dst + 16) = *(const uint4*)&QC[qrow*LDQ + qc0 + 16];
    *(uint4*)(dst + 24) = *(const uint4*)&QC[qrow*LDQ + qc0 + 24];
  }
}

// ---------------- out projection: 128x64x32 tiles, async staging, fp32 out -------
__global__ __launch_bounds__(256) void out_gemm(
    const unsigned short* __restrict__ ctx, const unsigned short* __restrict__ owb,
    const float* __restrict__ bias, float* __restrict__ out)
{
  __shared__ __align__(16) unsigned short As[128*32];
  __shared__ __align__(16) unsigned short Bs[64*32];
  const int tid = threadIdx.x;
  const int m0 = blockIdx.y * 128, n0 = blockIdx.x * 64;
  const int wave = tid >> 6, lane = tid & 63;
  const int wm = (wave >> 1) * 64, wn = (wave & 1) * 32;
  const int lrow = lane & 15, quad = lane >> 4;

  const int dl = lane >> 2, dkoff = (lane & 3) * 8;
  const int ar0 = wave*16 + dl, ar1 = (wave+4)*16 + dl;
  const int am0 = m0 + ar0, am1 = m0 + ar1;
  const size_t abase0 = ((size_t)((am0 >> 11)*NHEADS)*SEQ + (am0 & 2047))*HD;
  const size_t abase1 = ((size_t)((am1 >> 11)*NHEADS)*SEQ + (am1 & 2047))*HD;
  const unsigned short* gb = owb + (size_t)(n0 + wave*16 + dl) * D_MODEL + dkoff;
  unsigned short* la0 = &As[wave*512];
  unsigned short* la1 = &As[(wave+4)*512];
  unsigned short* lb  = &Bs[wave*512];

  f32x4 acc[4][2];
  #pragma unroll
  for (int i = 0; i < 4; i++)
    #pragma unroll
    for (int j = 0; j < 2; j++) acc[i][j] = (f32x4){0.f,0.f,0.f,0.f};

  for (int k0 = 0; k0 < D_MODEL; k0 += 32) {
    int kk = k0 + dkoff;
    int h = kk >> 6, hd = kk & 63;
    size_t hoff = (size_t)h * SEQ * HD + hd;
    __syncthreads();
    gl_lds16(ctx + abase0 + hoff, la0);
    gl_lds16(ctx + abase1 + hoff, la1);
    gl_lds16(gb + k0, lb);
    __syncthreads();
    bf16x8 af[4], bfr[2];
    #pragma unroll
    for (int mf = 0; mf < 4; mf++)
      af[mf] = *(const bf16x8*)&As[(wm + mf*16 + lrow)*32 + quad*8];
    #pragma unroll
    for (int nb = 0; nb < 2; nb++)
      bfr[nb] = *(const bf16x8*)&Bs[(wn + nb*16 + lrow)*32 + quad*8];
    #pragma unroll
    for (int mf = 0; mf < 4; mf++)
      #pragma unroll
      for (int nb = 0; nb < 2; nb++)
        acc[mf][nb] = __builtin_amdgcn_mfma_f32_16x16x32_bf16(af[mf], bfr[nb], acc[mf][nb], 0, 0, 0);
  }

  #pragma unroll
  for (int mf = 0; mf < 4; mf++) {
    #pragma unroll
    for (int nb = 0; nb < 2; nb++) {
      #pragma unroll
      for (int r = 0; r < 4; r++) {
        int mm = m0 + wm + mf*16 + quad*4 + r;
        int n  = n0 + wn + nb*16 + lrow;
        out[(size_t)mm * D_MODEL + n] = acc[mf][nb][r] + bias[n];
      }
    }
  }
}

extern "C" void kernel_launch(void* const* d_in, const int* in_sizes, int n_in,
                              void* d_out, int out_size, void* d_ws, size_t ws_size,
                              hipStream_t stream) {
  (void)in_sizes; (void)n_in; (void)out_size; (void)ws_size;
  const float* x      = (const float*)d_in[0];
  const float* Wqkv_w = (const float*)d_in[1];
  const float* Wqkv_b = (const float*)d_in[2];
  const float* out_w  = (const float*)d_in[3];
  const float* out_b  = (const float*)d_in[4];
  float* out = (float*)d_out;

  unsigned short* ws = (unsigned short*)d_ws;
  unsigned short* xb  = ws;                              // 4.19M elems; reused as ctx
  unsigned short* wqb = ws + CVT_N1;                     // 3.15M
  unsigned short* owb = ws + CVT_N1 + CVT_N2;            // 1.05M
  unsigned short* q   = ws + CVT_N1 + CVT_N2 + CVT_N3;   // 4.19M each
  unsigned short* k   = q + (size_t)NROWS*D_MODEL;
  unsigned short* vT  = k + (size_t)NROWS*D_MODEL;       // [bh][d][s] transposed
  unsigned short* ctx = xb;                              // alias: xb dead after qkv

  cvt_all<<<(CVT_N1+CVT_N2+CVT_N3)/(256*8), 256, 0, stream>>>(x, Wqkv_w, out_w, xb, wqb, owb);
  qkv_gemm<<<dim3(NQKV/128, NROWS/128), 256, 0, stream>>>(xb, wqb, Wqkv_b, q, k, vT);
  attn3<<<dim3(BATCH*NHEADS, SEQ/128), 256, 0, stream>>>(q, k, vT, ctx);
  out_gemm<<<dim3(D_MODEL/64, NROWS/128), 256, 0, stream>>>(ctx, owb, out_b, out);
}

// Round 9
// 255.466 us; speedup vs baseline: 2.4321x; 1.0028x over previous
//
#include <hip/hip_runtime.h>

// MHR_76965813945133: x->QKV proj -> 3x causal MHA (Q<-ctx, K/V fixed) -> out proj.
// B=2, S=2048, D=1024, NH=16, HD=64. bf16 MFMA compute, fp32 accum.
// R9: (1) attn3 LDQ 72->80: bank-uniform b128/b64 frag reads (was 2x floor on b64).
//     (2) qkv/out GEMMs: BK=64 (half the barrier drains) + XOR k-group swizzle
//         (source-side, DMA-compatible) -> conflict-free frag reads.

#define D_MODEL 1024
#define NHEADS  16
#define HD      64
#define SEQ     2048
#define BATCH   2
#define NROWS   (BATCH*SEQ)   // 4096
#define NQKV    (3*D_MODEL)   // 3072
#define SCL2F   0.1803368801111601f      // 0.125 * log2(e)
#define MASK2   (-14426.950408889634f)   // -10000 * log2(e)

typedef __bf16 bf16x8 __attribute__((ext_vector_type(8)));
typedef float  f32x4  __attribute__((ext_vector_type(4)));
typedef unsigned short us8 __attribute__((ext_vector_type(8)));
typedef unsigned short us4 __attribute__((ext_vector_type(4)));
typedef short  s16x4  __attribute__((ext_vector_type(4)));

__device__ __forceinline__ unsigned short f2bf(float f) {
  unsigned int u = __float_as_uint(f);
  u = (u + 0x7fffu + ((u >> 16) & 1u)) >> 16;   // RNE
  return (unsigned short)u;
}

union Pack8 { us8 v; unsigned short e[8]; };
union Pack4 { us4 v; unsigned short e[4]; };

__device__ __forceinline__ us8 cvt8(const float4 &a, const float4 &b) {
  Pack8 p;
  p.e[0]=f2bf(a.x); p.e[1]=f2bf(a.y); p.e[2]=f2bf(a.z); p.e[3]=f2bf(a.w);
  p.e[4]=f2bf(b.x); p.e[5]=f2bf(b.y); p.e[6]=f2bf(b.z); p.e[7]=f2bf(b.w);
  return p.v;
}

__device__ __forceinline__ void gl_lds16(const unsigned short* g, unsigned short* l) {
  __builtin_amdgcn_global_load_lds(
      (const __attribute__((address_space(1))) unsigned int*)g,
      (__attribute__((address_space(3))) unsigned int*)l, 16, 0, 0);
}

// ---------------- fp32 -> bf16 pre-convert (x, Wqkv_w, out_w) --------------------
#define CVT_N1 (NROWS*D_MODEL)    // 4194304
#define CVT_N2 (NQKV*D_MODEL)     // 3145728
#define CVT_N3 (D_MODEL*D_MODEL)  // 1048576

__global__ __launch_bounds__(256) void cvt_all(
    const float* __restrict__ x, const float* __restrict__ wq,
    const float* __restrict__ ow,
    unsigned short* __restrict__ xb, unsigned short* __restrict__ wqb,
    unsigned short* __restrict__ owb)
{
  size_t i = ((size_t)blockIdx.x * 256 + threadIdx.x) * 8;
  const float* src; unsigned short* dst; size_t off;
  if (i < CVT_N1)                { src = x;  dst = xb;  off = i; }
  else if (i < CVT_N1 + CVT_N2)  { src = wq; dst = wqb; off = i - CVT_N1; }
  else                           { src = ow; dst = owb; off = i - CVT_N1 - CVT_N2; }
  float4 a = *(const float4*)(src + off);
  float4 b = *(const float4*)(src + off + 4);
  *(us8*)(dst + off) = cvt8(a, b);
}

// ---------------- QKV GEMM: 128x128x64 tiles, async staging, XOR swizzle ---------
// Chunk = 8 rows x 64 cols (1 KB = one global_load_lds per wave). Source column
// group is (pg ^ dr) so LDS phys slot p of row r holds logical k-group p^(r&7);
// readers fetch logical g at phys g^(row&7) -> bank-uniform b128 frag reads.
__global__ __launch_bounds__(256) void qkv_gemm(
    const unsigned short* __restrict__ xb, const unsigned short* __restrict__ wqb,
    const float* __restrict__ bias,
    unsigned short* __restrict__ q, unsigned short* __restrict__ k,
    unsigned short* __restrict__ vT)
{
  __shared__ __align__(16) unsigned short As[128*64];
  __shared__ __align__(16) unsigned short Bs[128*64];
  const int tid = threadIdx.x;
  const int m0 = blockIdx.y * 128, n0 = blockIdx.x * 128;
  const int wave = tid >> 6, lane = tid & 63;
  const int wm = (wave >> 1) * 64, wn = (wave & 1) * 64;
  const int lrow = lane & 15, quad = lane >> 4;

  const int dr = lane >> 3;          // row within 8-row chunk
  const int pg = lane & 7;           // physical 16B slot within row
  const int sg = (pg ^ dr) * 8;      // swizzled source column (elems)
  const unsigned short* gA[4]; const unsigned short* gB[4];
  unsigned short *lA[4], *lB[4];
  #pragma unroll
  for (int i = 0; i < 4; i++) {
    int c = wave*4 + i;
    gA[i] = xb  + (size_t)(m0 + c*8 + dr) * D_MODEL + sg;
    gB[i] = wqb + (size_t)(n0 + c*8 + dr) * D_MODEL + sg;
    lA[i] = &As[c*512];
    lB[i] = &Bs[c*512];
  }
  const int px0 = (quad ^ (lrow & 7)) * 8;         // phys col of logical group quad
  const int px1 = ((quad + 4) ^ (lrow & 7)) * 8;   // phys col of logical group quad+4

  f32x4 acc[4][4];
  #pragma unroll
  for (int i = 0; i < 4; i++)
    #pragma unroll
    for (int j = 0; j < 4; j++) acc[i][j] = (f32x4){0.f,0.f,0.f,0.f};

  for (int k0 = 0; k0 < D_MODEL; k0 += 64) {
    __syncthreads();
    #pragma unroll
    for (int i = 0; i < 4; i++) { gl_lds16(gA[i] + k0, lA[i]); gl_lds16(gB[i] + k0, lB[i]); }
    __syncthreads();
    bf16x8 af[4][2], bfr[4][2];
    #pragma unroll
    for (int mf = 0; mf < 4; mf++) {
      int row = wm + mf*16 + lrow;
      af[mf][0] = *(const bf16x8*)&As[row*64 + px0];
      af[mf][1] = *(const bf16x8*)&As[row*64 + px1];
    }
    #pragma unroll
    for (int nb = 0; nb < 4; nb++) {
      int row = wn + nb*16 + lrow;
      bfr[nb][0] = *(const bf16x8*)&Bs[row*64 + px0];
      bfr[nb][1] = *(const bf16x8*)&Bs[row*64 + px1];
    }
    #pragma unroll
    for (int h = 0; h < 2; h++)
      #pragma unroll
      for (int mf = 0; mf < 4; mf++)
        #pragma unroll
        for (int nb = 0; nb < 4; nb++)
          acc[mf][nb] = __builtin_amdgcn_mfma_f32_16x16x32_bf16(af[mf][h], bfr[nb][h], acc[mf][nb], 0, 0, 0);
  }

  // epilogue: q/k scattered [B,NH,S,HD] (q pre-scaled); v transposed [bh][d][s]
  #pragma unroll
  for (int mf = 0; mf < 4; mf++) {
    #pragma unroll
    for (int nb = 0; nb < 4; nb++) {
      int n = n0 + wn + nb*16 + lrow;
      int which = n >> 10;
      int h  = (n >> 6) & 15;
      int hd = n & 63;
      int mb = m0 + wm + mf*16 + quad*4;
      int b  = mb >> 11;
      int s  = mb & 2047;
      float bi = bias[n];
      if (which == 2) {
        Pack4 p4;
        #pragma unroll
        for (int r = 0; r < 4; r++) p4.e[r] = f2bf(acc[mf][nb][r] + bi);
        *(us4*)&vT[((size_t)((b*NHEADS + h)*HD + hd))*SEQ + s] = p4.v;
      } else {
        unsigned short* dst = (which == 0) ? q : k;
        float scl = (which == 0) ? SCL2F : 1.0f;
        #pragma unroll
        for (int r = 0; r < 4; r++)
          dst[(size_t)((b*NHEADS + h)*SEQ + s + r)*HD + hd] = f2bf((acc[mf][nb][r] + bi) * scl);
      }
    }
  }
}

// ---------------- fused 3-rep causal flash attention ------------------------------
// 256-thr blocks (4 waves), 128-q tiles (32 q/wave), grid (bh=32, y=16).
// Mirror qt swizzle; ping-pong K/V (1 barrier/tile); Q chained via dead Vs buffer.
#define LDQ 80   // 160B rows (40 words): bank-uniform b128 AND b64 frag reads

__global__ __launch_bounds__(256) void attn3(
    const unsigned short* __restrict__ qg,
    const unsigned short* __restrict__ kg,
    const unsigned short* __restrict__ vTg,
    unsigned short* __restrict__ ctx)
{
  __shared__ __align__(16) unsigned short Ks[2][64*LDQ];
  __shared__ __align__(16) unsigned short Vs[2][64*LDQ];   // Vs[d][s]; also Q-chain buf
  unsigned short* QC = &Vs[0][0];                          // 128 rows x LDQ (spans Vs)

  const int tid  = threadIdx.x;
  const int w    = tid >> 6, lane = tid & 63;
  const int lrow = lane & 15, quad = lane >> 4;
  const int bh = blockIdx.x;
  const int yy = blockIdx.y;
  const int base = (blockIdx.x + yy) & 7;          // 0..7 (mirror permutation)
  const int qt = (yy < 8) ? base : (15 - base);
  const unsigned short* qbase = qg  + (size_t)bh * SEQ * HD;
  const unsigned short* kbase = kg  + (size_t)bh * SEQ * HD;
  const unsigned short* vbase = vTg + (size_t)bh * HD * SEQ;
  unsigned short* cbase = ctx + (size_t)bh * SEQ * HD;

  const int srow = tid >> 2;                       // 64x64 staging map
  const int sco  = (tid & 3) * 16;
  const int qrow = tid >> 1, qc0 = (tid & 1) * 32; // 128-row Q map

  // stage Q tile (rows qt*128..+127, pre-scaled) into QC
  {
    const unsigned short* src = qbase + (size_t)(qt*128 + qrow)*HD + qc0;
    *(uint4*)&QC[qrow*LDQ + qc0]      = *(const uint4*)src;
    *(uint4*)&QC[qrow*LDQ + qc0 + 8]  = *(const uint4*)(src + 8);
    *(uint4*)&QC[qrow*LDQ + qc0 + 16] = *(const uint4*)(src + 16);
    *(uint4*)&QC[qrow*LDQ + qc0 + 24] = *(const uint4*)(src + 24);
  }
  __syncthreads();

  // Q as K=32 B-operand frags: B[k=d=quad*8+j][n=q=lane&15]
  bf16x8 qb[2][2];
  #pragma unroll
  for (int qgi = 0; qgi < 2; qgi++) {
    qb[qgi][0] = *(const bf16x8*)&QC[(w*32 + qgi*16 + lrow)*LDQ + quad*8];
    qb[qgi][1] = *(const bf16x8*)&QC[(w*32 + qgi*16 + lrow)*LDQ + 32 + quad*8];
  }
  __syncthreads();   // qb reads done before kt=0 store overwrites Vs

  const int kmax = 2*qt + 1;          // last kt tile index
  const int qwbase = qt*128 + w*32;   // this wave's lowest q row

  for (int rep = 0; rep < 3; ++rep) {
    f32x4 od[2][4];
    #pragma unroll
    for (int qgi = 0; qgi < 2; qgi++)
      #pragma unroll
      for (int df = 0; df < 4; df++) od[qgi][df] = (f32x4){0.f,0.f,0.f,0.f};
    float ls[2] = {0.f, 0.f};

    // prefetch kt=0 (2 uint4 K + 2 uint4 V per thread)
    uint4 kr0, kr1, vr0, vr1;
    {
      const unsigned short* ks = kbase + (size_t)srow*HD + sco;
      kr0 = *(const uint4*)ks;  kr1 = *(const uint4*)(ks + 8);
      const unsigned short* vs = vbase + (size_t)srow*SEQ + sco;
      vr0 = *(const uint4*)vs;  vr1 = *(const uint4*)(vs + 8);
    }

    for (int kt = 0; kt <= kmax; ++kt) {
      const int b = kt & 1;
      *(uint4*)&Ks[b][srow*LDQ + sco]     = kr0;
      *(uint4*)&Ks[b][srow*LDQ + sco + 8] = kr1;
      *(uint4*)&Vs[b][srow*LDQ + sco]     = vr0;
      *(uint4*)&Vs[b][srow*LDQ + sco + 8] = vr1;
      if (kt < kmax) {
        const unsigned short* ks = kbase + (size_t)((kt+1)*64 + srow)*HD + sco;
        kr0 = *(const uint4*)ks;  kr1 = *(const uint4*)(ks + 8);
        const unsigned short* vs = vbase + (size_t)srow*SEQ + (kt+1)*64 + sco;
        vr0 = *(const uint4*)vs;  vr1 = *(const uint4*)(vs + 8);
      }
      __syncthreads();   // the only barrier per tile

      const int sbase = kt*64;
      const bool skip = sbase > (qwbase + 31);        // wave fully masked
      if (!skip) {
        // scores: S^T = K * Q^T (K=32), A-frags shared across both q-groups
        f32x4 sc[2][4];
        #pragma unroll
        for (int sf = 0; sf < 4; sf++) {
          bf16x8 a0 = *(const bf16x8*)&Ks[b][(sf*16 + lrow)*LDQ + quad*8];
          bf16x8 a1 = *(const bf16x8*)&Ks[b][(sf*16 + lrow)*LDQ + 32 + quad*8];
          f32x4 z0 = (f32x4){0.f,0.f,0.f,0.f}, z1 = z0;
          z0 = __builtin_amdgcn_mfma_f32_16x16x32_bf16(a0, qb[0][0], z0, 0, 0, 0);
          z1 = __builtin_amdgcn_mfma_f32_16x16x32_bf16(a0, qb[1][0], z1, 0, 0, 0);
          z0 = __builtin_amdgcn_mfma_f32_16x16x32_bf16(a1, qb[0][1], z0, 0, 0, 0);
          z1 = __builtin_amdgcn_mfma_f32_16x16x32_bf16(a1, qb[1][1], z1, 0, 0, 0);
          sc[0][sf] = z0; sc[1][sf] = z1;
        }
        if (sbase + 63 > qwbase) {   // element mask (last two kt only)
          #pragma unroll
          for (int qgi = 0; qgi < 2; qgi++) {
            int ql = qwbase + qgi*16 + lrow;
            #pragma unroll
            for (int sf = 0; sf < 4; sf++)
              #pragma unroll
              for (int r = 0; r < 4; r++)
                if (sbase + sf*16 + quad*4 + r > ql) sc[qgi][sf][r] += MASK2;
          }
        }
        // p = exp2(s); P lands directly in K=16 B-layout
        s16x4 pf[2][4];
        #pragma unroll
        for (int qgi = 0; qgi < 2; qgi++) {
          float lp = 0.f;
          #pragma unroll
          for (int sf = 0; sf < 4; sf++) {
            Pack4 pk;
            #pragma unroll
            for (int r = 0; r < 4; r++) {
              float pe = __builtin_amdgcn_exp2f(sc[qgi][sf][r]);
              lp += pe;
              pk.e[r] = __builtin_bit_cast(unsigned short, (__bf16)pe);
            }
            pf[qgi][sf] = __builtin_bit_cast(s16x4, pk.v);
          }
          ls[qgi] += lp;
        }
        // PV: O^T += V^T * P^T (K=16)
        #pragma unroll
        for (int df = 0; df < 4; df++) {
          s16x4 v0 = *(const s16x4*)&Vs[b][(df*16 + lrow)*LDQ +  0 + quad*4];
          s16x4 v1 = *(const s16x4*)&Vs[b][(df*16 + lrow)*LDQ + 16 + quad*4];
          s16x4 v2 = *(const s16x4*)&Vs[b][(df*16 + lrow)*LDQ + 32 + quad*4];
          s16x4 v3 = *(const s16x4*)&Vs[b][(df*16 + lrow)*LDQ + 48 + quad*4];
          od[0][df] = __builtin_amdgcn_mfma_f32_16x16x16bf16_1k(v0, pf[0][0], od[0][df], 0, 0, 0);
          od[1][df] = __builtin_amdgcn_mfma_f32_16x16x16bf16_1k(v0, pf[1][0], od[1][df], 0, 0, 0);
          od[0][df] = __builtin_amdgcn_mfma_f32_16x16x16bf16_1k(v1, pf[0][1], od[0][df], 0, 0, 0);
          od[1][df] = __builtin_amdgcn_mfma_f32_16x16x16bf16_1k(v1, pf[1][1], od[1][df], 0, 0, 0);
          od[0][df] = __builtin_amdgcn_mfma_f32_16x16x16bf16_1k(v2, pf[0][2], od[0][df], 0, 0, 0);
          od[1][df] = __builtin_amdgcn_mfma_f32_16x16x16bf16_1k(v2, pf[1][2], od[1][df], 0, 0, 0);
          od[0][df] = __builtin_amdgcn_mfma_f32_16x16x16bf16_1k(v3, pf[0][3], od[0][df], 0, 0, 0);
          od[1][df] = __builtin_amdgcn_mfma_f32_16x16x16bf16_1k(v3, pf[1][3], od[1][df], 0, 0, 0);
        }
      }
    } // kt

    // reduce l across quads (q id depends only on lane&15)
    #pragma unroll
    for (int qgi = 0; qgi < 2; qgi++) {
      ls[qgi] += __shfl_xor(ls[qgi], 16);
      ls[qgi] += __shfl_xor(ls[qgi], 32);
    }

    __syncthreads();   // all Ks/Vs readers done; QC (=Vs) is free
    #pragma unroll
    for (int qgi = 0; qgi < 2; qgi++) {
      float f = ((rep < 2) ? SCL2F : 1.0f) / ls[qgi];
      #pragma unroll
      for (int df = 0; df < 4; df++) {
        Pack4 pk;
        #pragma unroll
        for (int r = 0; r < 4; r++)
          pk.e[r] = __builtin_bit_cast(unsigned short, (__bf16)(od[qgi][df][r] * f));
        *(us4*)&QC[(w*32 + qgi*16 + lrow)*LDQ + df*16 + quad*4] = pk.v;
      }
    }
    __syncthreads();
    if (rep < 2) {   // reload chained Q frags
      #pragma unroll
      for (int qgi = 0; qgi < 2; qgi++) {
        qb[qgi][0] = *(const bf16x8*)&QC[(w*32 + qgi*16 + lrow)*LDQ + quad*8];
        qb[qgi][1] = *(const bf16x8*)&QC[(w*32 + qgi*16 + lrow)*LDQ + 32 + quad*8];
      }
      __syncthreads();   // reloads done before next rep's kt=0 store to Vs
    }
  } // rep

  {   // coalesced ctx store from QC
    unsigned short* dst = cbase + (size_t)(qt*128 + qrow)*HD + qc0;
    *(uint4*)dst        = *(const uint4*)&QC[qrow*LDQ + qc0];
    *(uint4*)(dst + 8)  = *(const uint4*)&QC[qrow*LDQ + qc0 + 8];
    *(uint4*)(dst + 16) = *(const uint4*)&QC[qrow*LDQ + qc0 + 16];
    *(uint4*)(dst + 24) = *(const uint4*)&QC[qrow*LDQ + qc0 + 24];
  }
}

// ---------------- out projection: 128x64x64 tiles, async staging, swizzled -------
__global__ __launch_bounds__(256) void out_gemm(
    const unsigned short* __restrict__ ctx, const unsigned short* __restrict__ owb,
    const float* __restrict__ bias, float* __restrict__ out)
{
  __shared__ __align__(16) unsigned short As[128*64];
  __shared__ __align__(16) unsigned short Bs[64*64];
  const int tid = threadIdx.x;
  const int m0 = blockIdx.y * 128, n0 = blockIdx.x * 64;
  const int wave = tid >> 6, lane = tid & 63;
  const int wm = (wave >> 1) * 64, wn = (wave & 1) * 32;
  const int lrow = lane & 15, quad = lane >> 4;

  const int dr = lane >> 3, pg = lane & 7;
  const int sg = (pg ^ dr) * 8;
  // A: 16 chunks (rows c*8..+7), wave takes 4; gather base per row
  size_t aoff[4]; unsigned short* lA[4];
  #pragma unroll
  for (int i = 0; i < 4; i++) {
    int c = wave*4 + i;
    int row = m0 + c*8 + dr;
    aoff[i] = ((size_t)((row >> 11)*NHEADS)*SEQ + (row & 2047))*HD + sg;
    lA[i] = &As[c*512];
  }
  // B: 8 chunks, wave takes 2
  const unsigned short* gB[2]; unsigned short* lB[2];
  #pragma unroll
  for (int j = 0; j < 2; j++) {
    int c = wave*2 + j;
    gB[j] = owb + (size_t)(n0 + c*8 + dr) * D_MODEL + sg;
    lB[j] = &Bs[c*512];
  }
  const int px0 = (quad ^ (lrow & 7)) * 8;
  const int px1 = ((quad + 4) ^ (lrow & 7)) * 8;

  f32x4 acc[4][2];
  #pragma unroll
  for (int i = 0; i < 4; i++)
    #pragma unroll
    for (int j = 0; j < 2; j++) acc[i][j] = (f32x4){0.f,0.f,0.f,0.f};

  for (int k0 = 0; k0 < D_MODEL; k0 += 64) {
    size_t hoff = (size_t)(k0 >> 6) * SEQ * HD;
    __syncthreads();
    #pragma unroll
    for (int i = 0; i < 4; i++) gl_lds16(ctx + aoff[i] + hoff, lA[i]);
    #pragma unroll
    for (int j = 0; j < 2; j++) gl_lds16(gB[j] + k0, lB[j]);
    __syncthreads();
    bf16x8 af[4][2], bfr[2][2];
    #pragma unroll
    for (int mf = 0; mf < 4; mf++) {
      int row = wm + mf*16 + lrow;
      af[mf][0] = *(const bf16x8*)&As[row*64 + px0];
      af[mf][1] = *(const bf16x8*)&As[row*64 + px1];
    }
    #pragma unroll
    for (int nb = 0; nb < 2; nb++) {
      int row = wn + nb*16 + lrow;
      bfr[nb][0] = *(const bf16x8*)&Bs[row*64 + px0];
      bfr[nb][1] = *(const bf16x8*)&Bs[row*64 + px1];
    }
    #pragma unroll
    for (int h = 0; h < 2; h++)
      #pragma unroll
      for (int mf = 0; mf < 4; mf++)
        #pragma unroll
        for (int nb = 0; nb < 2; nb++)
          acc[mf][nb] = __builtin_amdgcn_mfma_f32_16x16x32_bf16(af[mf][h], bfr[nb][h], acc[mf][nb], 0, 0, 0);
  }

  #pragma unroll
  for (int mf = 0; mf < 4; mf++) {
    #pragma unroll
    for (int nb = 0; nb < 2; nb++) {
      #pragma unroll
      for (int r = 0; r < 4; r++) {
        int mm = m0 + wm + mf*16 + quad*4 + r;
        int n  = n0 + wn + nb*16 + lrow;
        out[(size_t)mm * D_MODEL + n] = acc[mf][nb][r] + bias[n];
      }
    }
  }
}

extern "C" void kernel_launch(void* const* d_in, const int* in_sizes, int n_in,
                              void* d_out, int out_size, void* d_ws, size_t ws_size,
                              hipStream_t stream) {
  (void)in_sizes; (void)n_in; (void)out_size; (void)ws_size;
  const float* x      = (const float*)d_in[0];
  const float* Wqkv_w = (const float*)d_in[1];
  const float* Wqkv_b = (const float*)d_in[2];
  const float* out_w  = (const float*)d_in[3];
  const float* out_b  = (const float*)d_in[4];
  float* out = (float*)d_out;

  unsigned short* ws = (unsigned short*)d_ws;
  unsigned short* xb  = ws;                              // 4.19M elems; reused as ctx
  unsigned short* wqb = ws + CVT_N1;                     // 3.15M
  unsigned short* owb = ws + CVT_N1 + CVT_N2;            // 1.05M
  unsigned short* q   = ws + CVT_N1 + CVT_N2 + CVT_N3;   // 4.19M each
  unsigned short* k   = q + (size_t)NROWS*D_MODEL;
  unsigned short* vT  = k + (size_t)NROWS*D_MODEL;       // [bh][d][s] transposed
  unsigned short* ctx = xb;                              // alias: xb dead after qkv

  cvt_all<<<(CVT_N1+CVT_N2+CVT_N3)/(256*8), 256, 0, stream>>>(x, Wqkv_w, out_w, xb, wqb, owb);
  qkv_gemm<<<dim3(NQKV/128, NROWS/128), 256, 0, stream>>>(xb, wqb, Wqkv_b, q, k, vT);
  attn3<<<dim3(BATCH*NHEADS, SEQ/128), 256, 0, stream>>>(q, k, vT, ctx);
  out_gemm<<<dim3(D_MODEL/64, NROWS/128), 256, 0, stream>>>(ctx, owb, out_b, out);
}

// Round 10
// 246.180 us; speedup vs baseline: 2.5239x; 1.0377x over previous
//
#include <hip/hip_runtime.h>

// MHR_76965813945133: x->QKV proj -> 3x causal MHA (Q<-ctx, K/V fixed) -> out proj.
// B=2, S=2048, D=1024, NH=16, HD=64. bf16 MFMA compute, fp32 accum.
// R10: attn3: (1) LDQ back to 72 — the 80 "fix" DOUBLED conflicts (R9 post-mortem:
//      72's (lrow+quad)%8 group map is the uniform one); (2) two KV tiles staged
//      per barrier (4 K + 4 V buffers, 73.7KB — grid gives only 2 blocks/CU so the
//      spare LDS was free), halving barrier count; 2-tile-deep register prefetch.
//      GEMMs kept from R9 (BK=64 + XOR swizzle, ~13us win).

#define D_MODEL 1024
#define NHEADS  16
#define HD      64
#define SEQ     2048
#define BATCH   2
#define NROWS   (BATCH*SEQ)   // 4096
#define NQKV    (3*D_MODEL)   // 3072
#define SCL2F   0.1803368801111601f      // 0.125 * log2(e)
#define MASK2   (-14426.950408889634f)   // -10000 * log2(e)

typedef __bf16 bf16x8 __attribute__((ext_vector_type(8)));
typedef float  f32x4  __attribute__((ext_vector_type(4)));
typedef unsigned short us8 __attribute__((ext_vector_type(8)));
typedef unsigned short us4 __attribute__((ext_vector_type(4)));
typedef short  s16x4  __attribute__((ext_vector_type(4)));

__device__ __forceinline__ unsigned short f2bf(float f) {
  unsigned int u = __float_as_uint(f);
  u = (u + 0x7fffu + ((u >> 16) & 1u)) >> 16;   // RNE
  return (unsigned short)u;
}

union Pack8 { us8 v; unsigned short e[8]; };
union Pack4 { us4 v; unsigned short e[4]; };

__device__ __forceinline__ us8 cvt8(const float4 &a, const float4 &b) {
  Pack8 p;
  p.e[0]=f2bf(a.x); p.e[1]=f2bf(a.y); p.e[2]=f2bf(a.z); p.e[3]=f2bf(a.w);
  p.e[4]=f2bf(b.x); p.e[5]=f2bf(b.y); p.e[6]=f2bf(b.z); p.e[7]=f2bf(b.w);
  return p.v;
}

__device__ __forceinline__ void gl_lds16(const unsigned short* g, unsigned short* l) {
  __builtin_amdgcn_global_load_lds(
      (const __attribute__((address_space(1))) unsigned int*)g,
      (__attribute__((address_space(3))) unsigned int*)l, 16, 0, 0);
}

// ---------------- fp32 -> bf16 pre-convert (x, Wqkv_w, out_w) --------------------
#define CVT_N1 (NROWS*D_MODEL)    // 4194304
#define CVT_N2 (NQKV*D_MODEL)     // 3145728
#define CVT_N3 (D_MODEL*D_MODEL)  // 1048576

__global__ __launch_bounds__(256) void cvt_all(
    const float* __restrict__ x, const float* __restrict__ wq,
    const float* __restrict__ ow,
    unsigned short* __restrict__ xb, unsigned short* __restrict__ wqb,
    unsigned short* __restrict__ owb)
{
  size_t i = ((size_t)blockIdx.x * 256 + threadIdx.x) * 8;
  const float* src; unsigned short* dst; size_t off;
  if (i < CVT_N1)                { src = x;  dst = xb;  off = i; }
  else if (i < CVT_N1 + CVT_N2)  { src = wq; dst = wqb; off = i - CVT_N1; }
  else                           { src = ow; dst = owb; off = i - CVT_N1 - CVT_N2; }
  float4 a = *(const float4*)(src + off);
  float4 b = *(const float4*)(src + off + 4);
  *(us8*)(dst + off) = cvt8(a, b);
}

// ---------------- QKV GEMM: 128x128x64 tiles, async staging, XOR swizzle ---------
__global__ __launch_bounds__(256) void qkv_gemm(
    const unsigned short* __restrict__ xb, const unsigned short* __restrict__ wqb,
    const float* __restrict__ bias,
    unsigned short* __restrict__ q, unsigned short* __restrict__ k,
    unsigned short* __restrict__ vT)
{
  __shared__ __align__(16) unsigned short As[128*64];
  __shared__ __align__(16) unsigned short Bs[128*64];
  const int tid = threadIdx.x;
  const int m0 = blockIdx.y * 128, n0 = blockIdx.x * 128;
  const int wave = tid >> 6, lane = tid & 63;
  const int wm = (wave >> 1) * 64, wn = (wave & 1) * 64;
  const int lrow = lane & 15, quad = lane >> 4;

  const int dr = lane >> 3;          // row within 8-row chunk
  const int pg = lane & 7;           // physical 16B slot within row
  const int sg = (pg ^ dr) * 8;      // swizzled source column (elems)
  const unsigned short* gA[4]; const unsigned short* gB[4];
  unsigned short *lA[4], *lB[4];
  #pragma unroll
  for (int i = 0; i < 4; i++) {
    int c = wave*4 + i;
    gA[i] = xb  + (size_t)(m0 + c*8 + dr) * D_MODEL + sg;
    gB[i] = wqb + (size_t)(n0 + c*8 + dr) * D_MODEL + sg;
    lA[i] = &As[c*512];
    lB[i] = &Bs[c*512];
  }
  const int px0 = (quad ^ (lrow & 7)) * 8;
  const int px1 = ((quad + 4) ^ (lrow & 7)) * 8;

  f32x4 acc[4][4];
  #pragma unroll
  for (int i = 0; i < 4; i++)
    #pragma unroll
    for (int j = 0; j < 4; j++) acc[i][j] = (f32x4){0.f,0.f,0.f,0.f};

  for (int k0 = 0; k0 < D_MODEL; k0 += 64) {
    __syncthreads();
    #pragma unroll
    for (int i = 0; i < 4; i++) { gl_lds16(gA[i] + k0, lA[i]); gl_lds16(gB[i] + k0, lB[i]); }
    __syncthreads();
    bf16x8 af[4][2], bfr[4][2];
    #pragma unroll
    for (int mf = 0; mf < 4; mf++) {
      int row = wm + mf*16 + lrow;
      af[mf][0] = *(const bf16x8*)&As[row*64 + px0];
      af[mf][1] = *(const bf16x8*)&As[row*64 + px1];
    }
    #pragma unroll
    for (int nb = 0; nb < 4; nb++) {
      int row = wn + nb*16 + lrow;
      bfr[nb][0] = *(const bf16x8*)&Bs[row*64 + px0];
      bfr[nb][1] = *(const bf16x8*)&Bs[row*64 + px1];
    }
    #pragma unroll
    for (int h = 0; h < 2; h++)
      #pragma unroll
      for (int mf = 0; mf < 4; mf++)
        #pragma unroll
        for (int nb = 0; nb < 4; nb++)
          acc[mf][nb] = __builtin_amdgcn_mfma_f32_16x16x32_bf16(af[mf][h], bfr[nb][h], acc[mf][nb], 0, 0, 0);
  }

  #pragma unroll
  for (int mf = 0; mf < 4; mf++) {
    #pragma unroll
    for (int nb = 0; nb < 4; nb++) {
      int n = n0 + wn + nb*16 + lrow;
      int which = n >> 10;
      int h  = (n >> 6) & 15;
      int hd = n & 63;
      int mb = m0 + wm + mf*16 + quad*4;
      int b  = mb >> 11;
      int s  = mb & 2047;
      float bi = bias[n];
      if (which == 2) {
        Pack4 p4;
        #pragma unroll
        for (int r = 0; r < 4; r++) p4.e[r] = f2bf(acc[mf][nb][r] + bi);
        *(us4*)&vT[((size_t)((b*NHEADS + h)*HD + hd))*SEQ + s] = p4.v;
      } else {
        unsigned short* dst = (which == 0) ? q : k;
        float scl = (which == 0) ? SCL2F : 1.0f;
        #pragma unroll
        for (int r = 0; r < 4; r++)
          dst[(size_t)((b*NHEADS + h)*SEQ + s + r)*HD + hd] = f2bf((acc[mf][nb][r] + bi) * scl);
      }
    }
  }
}

// ---------------- fused 3-rep causal flash attention ------------------------------
// 256-thr blocks (4 waves), 128-q tiles (32 q/wave), grid (bh=32, y=16).
// Mirror qt swizzle. 4 K + 4 V buffers: TWO tiles staged per barrier (pair loop);
// 2-tile-deep register prefetch. Q chained via dead Vs buffers.
#define LDQ 72   // 144B rows: b128 groups (lrow+quad)%8 -> bank-uniform (R9 errata)

__global__ __launch_bounds__(256) void attn3(
    const unsigned short* __restrict__ qg,
    const unsigned short* __restrict__ kg,
    const unsigned short* __restrict__ vTg,
    unsigned short* __restrict__ ctx)
{
  __shared__ __align__(16) unsigned short Ks[4][64*LDQ];
  __shared__ __align__(16) unsigned short Vs[4][64*LDQ];   // Vs[d][s]; [0..1] = Q-chain
  unsigned short* QC = &Vs[0][0];                          // 128 rows x LDQ

  const int tid  = threadIdx.x;
  const int w    = tid >> 6, lane = tid & 63;
  const int lrow = lane & 15, quad = lane >> 4;
  const int bh = blockIdx.x;
  const int yy = blockIdx.y;
  const int base = (blockIdx.x + yy) & 7;          // 0..7 (mirror permutation)
  const int qt = (yy < 8) ? base : (15 - base);
  const unsigned short* qbase = qg  + (size_t)bh * SEQ * HD;
  const unsigned short* kbase = kg  + (size_t)bh * SEQ * HD;
  const unsigned short* vbase = vTg + (size_t)bh * HD * SEQ;
  unsigned short* cbase = ctx + (size_t)bh * SEQ * HD;

  const int srow = tid >> 2;                       // 64x64 staging map
  const int sco  = (tid & 3) * 16;
  const int qrow = tid >> 1, qc0 = (tid & 1) * 32; // 128-row Q map

  // stage Q tile (rows qt*128..+127, pre-scaled) into QC
  {
    const unsigned short* src = qbase + (size_t)(qt*128 + qrow)*HD + qc0;
    *(uint4*)&QC[qrow*LDQ + qc0]      = *(const uint4*)src;
    *(uint4*)&QC[qrow*LDQ + qc0 + 8]  = *(const uint4*)(src + 8);
    *(uint4*)&QC[qrow*LDQ + qc0 + 16] = *(const uint4*)(src + 16);
    *(uint4*)&QC[qrow*LDQ + qc0 + 24] = *(const uint4*)(src + 24);
  }
  __syncthreads();

  // Q as K=32 B-operand frags: B[k=d=quad*8+j][n=q=lane&15]
  bf16x8 qb[2][2];
  #pragma unroll
  for (int qgi = 0; qgi < 2; qgi++) {
    qb[qgi][0] = *(const bf16x8*)&QC[(w*32 + qgi*16 + lrow)*LDQ + quad*8];
    qb[qgi][1] = *(const bf16x8*)&QC[(w*32 + qgi*16 + lrow)*LDQ + 32 + quad*8];
  }
  __syncthreads();   // qb reads done before first stores overwrite Vs

  const int qwbase = qt*128 + w*32;   // this wave's lowest q row
  const int npair = qt + 1;           // tile pairs (tiles 2t, 2t+1); last = 2qt+1

  for (int rep = 0; rep < 3; ++rep) {
    f32x4 od[2][4];
    #pragma unroll
    for (int qgi = 0; qgi < 2; qgi++)
      #pragma unroll
      for (int df = 0; df < 4; df++) od[qgi][df] = (f32x4){0.f,0.f,0.f,0.f};
    float ls[2] = {0.f, 0.f};

    // prefetch pair 0 (tiles 0,1): 4 uint4 K + 4 uint4 V per thread
    uint4 ka0, ka1, kb0, kb1, va0, va1, vb0, vb1;
    {
      const unsigned short* ks = kbase + (size_t)srow*HD + sco;
      ka0 = *(const uint4*)ks;  ka1 = *(const uint4*)(ks + 8);
      kb0 = *(const uint4*)(ks + 64*HD);  kb1 = *(const uint4*)(ks + 64*HD + 8);
      const unsigned short* vs = vbase + (size_t)srow*SEQ + sco;
      va0 = *(const uint4*)vs;  va1 = *(const uint4*)(vs + 8);
      vb0 = *(const uint4*)(vs + 64);  vb1 = *(const uint4*)(vs + 64 + 8);
    }

    for (int t = 0; t < npair; ++t) {
      const int pb = (t & 1) * 2;    // buffer pair base {pb, pb+1}
      *(uint4*)&Ks[pb][srow*LDQ + sco]       = ka0;
      *(uint4*)&Ks[pb][srow*LDQ + sco + 8]   = ka1;
      *(uint4*)&Ks[pb+1][srow*LDQ + sco]     = kb0;
      *(uint4*)&Ks[pb+1][srow*LDQ + sco + 8] = kb1;
      *(uint4*)&Vs[pb][srow*LDQ + sco]       = va0;
      *(uint4*)&Vs[pb][srow*LDQ + sco + 8]   = va1;
      *(uint4*)&Vs[pb+1][srow*LDQ + sco]     = vb0;
      *(uint4*)&Vs[pb+1][srow*LDQ + sco + 8] = vb1;
      if (t + 1 < npair) {   // prefetch next pair (tiles 2t+2, 2t+3)
        const unsigned short* ks = kbase + (size_t)((2*t+2)*64 + srow)*HD + sco;
        ka0 = *(const uint4*)ks;  ka1 = *(const uint4*)(ks + 8);
        kb0 = *(const uint4*)(ks + 64*HD);  kb1 = *(const uint4*)(ks + 64*HD + 8);
        const unsigned short* vs = vbase + (size_t)srow*SEQ + (2*t+2)*64 + sco;
        va0 = *(const uint4*)vs;  va1 = *(const uint4*)(vs + 8);
        vb0 = *(const uint4*)(vs + 64);  vb1 = *(const uint4*)(vs + 64 + 8);
      }
      __syncthreads();   // ONE barrier per pair (2 tiles)

      #pragma unroll
      for (int half = 0; half < 2; ++half) {
        const int bb = pb + half;
        const int sbase = (2*t + half) * 64;
        if (sbase > qwbase + 31) continue;   // wave fully masked for this tile
        // scores: S^T = K * Q^T (K=32)
        f32x4 sc[2][4];
        #pragma unroll
        for (int sf = 0; sf < 4; sf++) {
          bf16x8 a0 = *(const bf16x8*)&Ks[bb][(sf*16 + lrow)*LDQ + quad*8];
          bf16x8 a1 = *(const bf16x8*)&Ks[bb][(sf*16 + lrow)*LDQ + 32 + quad*8];
          f32x4 z0 = (f32x4){0.f,0.f,0.f,0.f}, z1 = z0;
          z0 = __builtin_amdgcn_mfma_f32_16x16x32_bf16(a0, qb[0][0], z0, 0, 0, 0);
          z1 = __builtin_amdgcn_mfma_f32_16x16x32_bf16(a0, qb[1][0], z1, 0, 0, 0);
          z0 = __builtin_amdgcn_mfma_f32_16x16x32_bf16(a1, qb[0][1], z0, 0, 0, 0);
          z1 = __builtin_amdgcn_mfma_f32_16x16x32_bf16(a1, qb[1][1], z1, 0, 0, 0);
          sc[0][sf] = z0; sc[1][sf] = z1;
        }
        if (sbase + 63 > qwbase) {   // element mask (diag-adjacent tiles only)
          #pragma unroll
          for (int qgi = 0; qgi < 2; qgi++) {
            int ql = qwbase + qgi*16 + lrow;
            #pragma unroll
            for (int sf = 0; sf < 4; sf++)
              #pragma unroll
              for (int r = 0; r < 4; r++)
                if (sbase + sf*16 + quad*4 + r > ql) sc[qgi][sf][r] += MASK2;
          }
        }
        // p = exp2(s); P lands directly in K=16 B-layout
        s16x4 pf[2][4];
        #pragma unroll
        for (int qgi = 0; qgi < 2; qgi++) {
          float lp = 0.f;
          #pragma unroll
          for (int sf = 0; sf < 4; sf++) {
            Pack4 pk;
            #pragma unroll
            for (int r = 0; r < 4; r++) {
              float pe = __builtin_amdgcn_exp2f(sc[qgi][sf][r]);
              lp += pe;
              pk.e[r] = __builtin_bit_cast(unsigned short, (__bf16)pe);
            }
            pf[qgi][sf] = __builtin_bit_cast(s16x4, pk.v);
          }
          ls[qgi] += lp;
        }
        // PV: O^T += V^T * P^T (K=16)
        #pragma unroll
        for (int df = 0; df < 4; df++) {
          s16x4 v0 = *(const s16x4*)&Vs[bb][(df*16 + lrow)*LDQ +  0 + quad*4];
          s16x4 v1 = *(const s16x4*)&Vs[bb][(df*16 + lrow)*LDQ + 16 + quad*4];
          s16x4 v2 = *(const s16x4*)&Vs[bb][(df*16 + lrow)*LDQ + 32 + quad*4];
          s16x4 v3 = *(const s16x4*)&Vs[bb][(df*16 + lrow)*LDQ + 48 + quad*4];
          od[0][df] = __builtin_amdgcn_mfma_f32_16x16x16bf16_1k(v0, pf[0][0], od[0][df], 0, 0, 0);
          od[1][df] = __builtin_amdgcn_mfma_f32_16x16x16bf16_1k(v0, pf[1][0], od[1][df], 0, 0, 0);
          od[0][df] = __builtin_amdgcn_mfma_f32_16x16x16bf16_1k(v1, pf[0][1], od[0][df], 0, 0, 0);
          od[1][df] = __builtin_amdgcn_mfma_f32_16x16x16bf16_1k(v1, pf[1][1], od[1][df], 0, 0, 0);
          od[0][df] = __builtin_amdgcn_mfma_f32_16x16x16bf16_1k(v2, pf[0][2], od[0][df], 0, 0, 0);
          od[1][df] = __builtin_amdgcn_mfma_f32_16x16x16bf16_1k(v2, pf[1][2], od[1][df], 0, 0, 0);
          od[0][df] = __builtin_amdgcn_mfma_f32_16x16x16bf16_1k(v3, pf[0][3], od[0][df], 0, 0, 0);
          od[1][df] = __builtin_amdgcn_mfma_f32_16x16x16bf16_1k(v3, pf[1][3], od[1][df], 0, 0, 0);
        }
      } // half
    } // t

    // reduce l across quads (q id depends only on lane&15)
    #pragma unroll
    for (int qgi = 0; qgi < 2; qgi++) {
      ls[qgi] += __shfl_xor(ls[qgi], 16);
      ls[qgi] += __shfl_xor(ls[qgi], 32);
    }

    __syncthreads();   // all Ks/Vs readers done; QC (=Vs[0..1]) is free
    #pragma unroll
    for (int qgi = 0; qgi < 2; qgi++) {
      float f = ((rep < 2) ? SCL2F : 1.0f) / ls[qgi];
      #pragma unroll
      for (int df = 0; df < 4; df++) {
        Pack4 pk;
        #pragma unroll
        for (int r = 0; r < 4; r++)
          pk.e[r] = __builtin_bit_cast(unsigned short, (__bf16)(od[qgi][df][r] * f));
        *(us4*)&QC[(w*32 + qgi*16 + lrow)*LDQ + df*16 + quad*4] = pk.v;
      }
    }
    __syncthreads();
    if (rep < 2) {   // reload chained Q frags
      #pragma unroll
      for (int qgi = 0; qgi < 2; qgi++) {
        qb[qgi][0] = *(const bf16x8*)&QC[(w*32 + qgi*16 + lrow)*LDQ + quad*8];
        qb[qgi][1] = *(const bf16x8*)&QC[(w*32 + qgi*16 + lrow)*LDQ + 32 + quad*8];
      }
      __syncthreads();   // reloads done before next rep's stores to Vs
    }
  } // rep

  {   // coalesced ctx store from QC
    unsigned short* dst = cbase + (size_t)(qt*128 + qrow)*HD + qc0;
    *(uint4*)dst        = *(const uint4*)&QC[qrow*LDQ + qc0];
    *(uint4*)(dst + 8)  = *(const uint4*)&QC[qrow*LDQ + qc0 + 8];
    *(uint4*)(dst + 16) = *(const uint4*)&QC[qrow*LDQ + qc0 + 16];
    *(uint4*)(dst + 24) = *(const uint4*)&QC[qrow*LDQ + qc0 + 24];
  }
}

// ---------------- out projection: 128x64x64 tiles, async staging, swizzled -------
__global__ __launch_bounds__(256) void out_gemm(
    const unsigned short* __restrict__ ctx, const unsigned short* __restrict__ owb,
    const float* __restrict__ bias, float* __restrict__ out)
{
  __shared__ __align__(16) unsigned short As[128*64];
  __shared__ __align__(16) unsigned short Bs[64*64];
  const int tid = threadIdx.x;
  const int m0 = blockIdx.y * 128, n0 = blockIdx.x * 64;
  const int wave = tid >> 6, lane = tid & 63;
  const int wm = (wave >> 1) * 64, wn = (wave & 1) * 32;
  const int lrow = lane & 15, quad = lane >> 4;

  const int dr = lane >> 3, pg = lane & 7;
  const int sg = (pg ^ dr) * 8;
  size_t aoff[4]; unsigned short* lA[4];
  #pragma unroll
  for (int i = 0; i < 4; i++) {
    int c = wave*4 + i;
    int row = m0 + c*8 + dr;
    aoff[i] = ((size_t)((row >> 11)*NHEADS)*SEQ + (row & 2047))*HD + sg;
    lA[i] = &As[c*512];
  }
  const unsigned short* gB[2]; unsigned short* lB[2];
  #pragma unroll
  for (int j = 0; j < 2; j++) {
    int c = wave*2 + j;
    gB[j] = owb + (size_t)(n0 + c*8 + dr) * D_MODEL + sg;
    lB[j] = &Bs[c*512];
  }
  const int px0 = (quad ^ (lrow & 7)) * 8;
  const int px1 = ((quad + 4) ^ (lrow & 7)) * 8;

  f32x4 acc[4][2];
  #pragma unroll
  for (int i = 0; i < 4; i++)
    #pragma unroll
    for (int j = 0; j < 2; j++) acc[i][j] = (f32x4){0.f,0.f,0.f,0.f};

  for (int k0 = 0; k0 < D_MODEL; k0 += 64) {
    size_t hoff = (size_t)(k0 >> 6) * SEQ * HD;
    __syncthreads();
    #pragma unroll
    for (int i = 0; i < 4; i++) gl_lds16(ctx + aoff[i] + hoff, lA[i]);
    #pragma unroll
    for (int j = 0; j < 2; j++) gl_lds16(gB[j] + k0, lB[j]);
    __syncthreads();
    bf16x8 af[4][2], bfr[2][2];
    #pragma unroll
    for (int mf = 0; mf < 4; mf++) {
      int row = wm + mf*16 + lrow;
      af[mf][0] = *(const bf16x8*)&As[row*64 + px0];
      af[mf][1] = *(const bf16x8*)&As[row*64 + px1];
    }
    #pragma unroll
    for (int nb = 0; nb < 2; nb++) {
      int row = wn + nb*16 + lrow;
      bfr[nb][0] = *(const bf16x8*)&Bs[row*64 + px0];
      bfr[nb][1] = *(const bf16x8*)&Bs[row*64 + px1];
    }
    #pragma unroll
    for (int h = 0; h < 2; h++)
      #pragma unroll
      for (int mf = 0; mf < 4; mf++)
        #pragma unroll
        for (int nb = 0; nb < 2; nb++)
          acc[mf][nb] = __builtin_amdgcn_mfma_f32_16x16x32_bf16(af[mf][h], bfr[nb][h], acc[mf][nb], 0, 0, 0);
  }

  #pragma unroll
  for (int mf = 0; mf < 4; mf++) {
    #pragma unroll
    for (int nb = 0; nb < 2; nb++) {
      #pragma unroll
      for (int r = 0; r < 4; r++) {
        int mm = m0 + wm + mf*16 + quad*4 + r;
        int n  = n0 + wn + nb*16 + lrow;
        out[(size_t)mm * D_MODEL + n] = acc[mf][nb][r] + bias[n];
      }
    }
  }
}

extern "C" void kernel_launch(void* const* d_in, const int* in_sizes, int n_in,
                              void* d_out, int out_size, void* d_ws, size_t ws_size,
                              hipStream_t stream) {
  (void)in_sizes; (void)n_in; (void)out_size; (void)ws_size;
  const float* x      = (const float*)d_in[0];
  const float* Wqkv_w = (const float*)d_in[1];
  const float* Wqkv_b = (const float*)d_in[2];
  const float* out_w  = (const float*)d_in[3];
  const float* out_b  = (const float*)d_in[4];
  float* out = (float*)d_out;

  unsigned short* ws = (unsigned short*)d_ws;
  unsigned short* xb  = ws;                              // 4.19M elems; reused as ctx
  unsigned short* wqb = ws + CVT_N1;                     // 3.15M
  unsigned short* owb = ws + CVT_N1 + CVT_N2;            // 1.05M
  unsigned short* q   = ws + CVT_N1 + CVT_N2 + CVT_N3;   // 4.19M each
  unsigned short* k   = q + (size_t)NROWS*D_MODEL;
  unsigned short* vT  = k + (size_t)NROWS*D_MODEL;       // [bh][d][s] transposed
  unsigned short* ctx = xb;                              // alias: xb dead after qkv

  cvt_all<<<(CVT_N1+CVT_N2+CVT_N3)/(256*8), 256, 0, stream>>>(x, Wqkv_w, out_w, xb, wqb, owb);
  qkv_gemm<<<dim3(NQKV/128, NROWS/128), 256, 0, stream>>>(xb, wqb, Wqkv_b, q, k, vT);
  attn3<<<dim3(BATCH*NHEADS, SEQ/128), 256, 0, stream>>>(q, k, vT, ctx);
  out_gemm<<<dim3(D_MODEL/64, NROWS/128), 256, 0, stream>>>(ctx, owb, out_b, out);
}